// Round 16
// baseline (477.204 us; speedup 1.0000x reference)
//
#include <hip/hip_runtime.h>
#include <hip/hip_fp16.h>
#include <math.h>

#define NN 100000
#define NE 500000
#define NG 128
#define ND 91
#define ED 20
#define H  128
#define NL 3
#define EPSF 1e-5f
#define EPB 32          // edges per block in aggregation
#define NB64 ((NN + 63) / 64)
#define NSC ((NN + 1023) / 1024)

typedef _Float16 f16;
typedef _Float16 f16x2 __attribute__((ext_vector_type(2)));
typedef _Float16 f16x8 __attribute__((ext_vector_type(8)));
typedef float    f32x4 __attribute__((ext_vector_type(4)));

// swizzled LDS byte offset for a [64][128] f16 tile (row stride 256 B)
__device__ __forceinline__ int swz(int row, int colbyte) {
    return (row * 256 + colbyte) ^ ((row & 7) << 4);
}

// order-preserving float<->uint for atomicMax
__device__ __forceinline__ unsigned fenc(float f) {
    unsigned u = __float_as_uint(f);
    return (u & 0x80000000u) ? ~u : (u | 0x80000000u);
}
__device__ __forceinline__ float fdec(unsigned key) {
    unsigned u = (key & 0x80000000u) ? (key & 0x7FFFFFFFu) : ~key;
    return __uint_as_float(u);
}

// ---------------------------------------------------------------------------
// Fold edge-feature path: Wec[l] = ee_W @ msg_W1[l][2H:3H,:]
// ---------------------------------------------------------------------------
__global__ void fold_edge_weights(const float* __restrict__ eeW,
                                  const float* __restrict__ eeb,
                                  const float* __restrict__ msgW1,
                                  const float* __restrict__ msgb1,
                                  float* __restrict__ Wec,
                                  float* __restrict__ bec) {
    int l = blockIdx.y;
    int k = blockIdx.x;                        // 0..ED (ED => bias row)
    int c = threadIdx.x;
    const float* W1e = msgW1 + (size_t)l * 3 * H * H + (size_t)2 * H * H;
    if (k < ED) {
        float acc = 0.f;
        for (int m = 0; m < H; ++m) acc += eeW[k * H + m] * W1e[m * H + c];
        Wec[((size_t)l * ED + k) * H + c] = acc;
    } else {
        float acc = msgb1[l * H + c];
        for (int m = 0; m < H; ++m) acc += eeb[m] * W1e[m * H + c];
        bec[(size_t)l * H + c] = acc;
    }
}

// pack Wec into f16 pairs
__global__ void pack_wec(const float* __restrict__ Wec,
                         f16x2* __restrict__ wecp) {
    int l = blockIdx.x, k2 = blockIdx.y, c = threadIdx.x;
    f16x2 v;
    v[0] = (f16)Wec[((size_t)l * ED + 2 * k2) * H + c];
    v[1] = (f16)Wec[((size_t)l * ED + 2 * k2 + 1) * H + c];
    wecp[((size_t)l * (ED / 2) + k2) * H + c] = v;
}

// ---------------------------------------------------------------------------
// Fold msg_W2 into update weights
// ---------------------------------------------------------------------------
__global__ void fold_W2u(const float* __restrict__ msgW2,
                         const float* __restrict__ msgb2,
                         const float* __restrict__ updW,
                         float* __restrict__ W2u,
                         float* __restrict__ b2u) {
    int l = blockIdx.y;
    int k = blockIdx.x;                        // 0..H (H => bias row)
    int c = threadIdx.x;
    const float* Wbot = updW + (size_t)l * 2 * H * H + (size_t)H * H;
    if (k < H) {
        const float* w2row = msgW2 + (size_t)l * H * H + (size_t)k * H;
        float acc = 0.f;
        for (int m = 0; m < H; ++m) acc += w2row[m] * Wbot[m * H + c];
        W2u[((size_t)l * H + k) * H + c] = acc;
    } else {
        const float* b2 = msgb2 + (size_t)l * H;
        float acc = 0.f;
        for (int m = 0; m < H; ++m) acc += b2[m] * Wbot[m * H + c];
        b2u[(size_t)l * H + c] = acc;
    }
}

// ---------------------------------------------------------------------------
// W1s: fragment-major pre-swizzled GEMM1 weights.
// ---------------------------------------------------------------------------
__global__ void make_W1s(const float* __restrict__ updW,
                         const float* __restrict__ W2u,
                         f16* __restrict__ W1s) {
    int l = blockIdx.x, frag = blockIdx.y, lane = threadIdx.x;  // 64 threads
    int cf = frag >> 3, kc = frag & 7;
    int col = cf * 16 + (lane & 15);
    int k0 = kc * 32 + (lane >> 4) * 8;
    f16* out = W1s + ((size_t)l * 64 + frag) * 512 + lane * 8;
    for (int j = 0; j < 8; ++j) {
        int k = k0 + j;
        float v = (k < H) ? updW[(size_t)l * 2 * H * H + (size_t)k * H + col]
                          : W2u[(size_t)l * H * H + (size_t)(k - H) * H + col];
        out[j] = (f16)v;
    }
}

// ---------------------------------------------------------------------------
// W2s: fragment-major pre-swizzled GEMM2 weights.
// ---------------------------------------------------------------------------
__global__ void make_W2s(const float* __restrict__ msgW1,
                         f16* __restrict__ W2s) {
    int l = blockIdx.x, frag = blockIdx.y, lane = threadIdx.x;  // 64 threads
    int wave = frag >> 4, mf = (frag >> 2) & 3, kc = frag & 3;
    int oc = wave * 64 + mf * 16 + (lane & 15);
    int k0 = kc * 32 + (lane >> 4) * 8;
    const float* W1 = msgW1 + (size_t)l * 3 * H * H;
    f16* out = W2s + ((size_t)l * 64 + frag) * 512 + lane * 8;
    for (int j = 0; j < 8; ++j) {
        int k = k0 + j;
        float v = W1[(size_t)((oc < H ? 0 : H) + k) * H + (oc & (H - 1))];
        out[j] = (f16)v;
    }
}

// ---------------------------------------------------------------------------
// Wenc: fragment-major encode weights (K padded 96)
// ---------------------------------------------------------------------------
__global__ void make_Wenc(const float* __restrict__ neW,
                          f16* __restrict__ Wenc) {
    int frag = blockIdx.x, lane = threadIdx.x;  // 24 frags, 64 threads
    int cf = frag / 3, kc = frag % 3;
    int col = cf * 16 + (lane & 15);
    int k0 = kc * 32 + (lane >> 4) * 8;
    f16* out = Wenc + (size_t)frag * 512 + lane * 8;
    for (int j = 0; j < 8; ++j) {
        int k = k0 + j;
        out[j] = (k < ND) ? (f16)neW[(size_t)k * H + col] : (f16)0.f;
    }
}

// ---------------------------------------------------------------------------
// CSR build over dst
// ---------------------------------------------------------------------------
__global__ void csr_count(const int* __restrict__ dst, int* __restrict__ deg) {
    int e = blockIdx.x * blockDim.x + threadIdx.x;
    if (e < NE) atomicAdd(&deg[dst[e]], 1);
}

__global__ void scan_p1(const int* __restrict__ deg,
                        int* __restrict__ part, int* __restrict__ bsum) {
    __shared__ int ws[16];
    int t = threadIdx.x, lane = t & 63, w = t >> 6;
    int i = blockIdx.x * 1024 + t;
    int v = (i < NN) ? deg[i] : 0;
    int inc = v;
    #pragma unroll
    for (int off = 1; off < 64; off <<= 1) {
        int u = __shfl_up(inc, off, 64);
        if (lane >= off) inc += u;
    }
    if (lane == 63) ws[w] = inc;
    __syncthreads();
    if (t == 0) {
        int run = 0;
        #pragma unroll
        for (int q = 0; q < 16; ++q) { int tmp = ws[q]; ws[q] = run; run += tmp; }
        bsum[blockIdx.x] = run;
    }
    __syncthreads();
    if (i < NN) part[i] = ws[w] + inc - v;
}

__global__ void scan_p2(int* __restrict__ bsum) {
    if (threadIdx.x == 0) {
        int run = 0;
        for (int q = 0; q < NSC; ++q) { int tmp = bsum[q]; bsum[q] = run; run += tmp; }
    }
}

__global__ void scan_p3(const int* __restrict__ part, const int* __restrict__ bsum,
                        int* __restrict__ rowstart) {
    int i = blockIdx.x * 1024 + threadIdx.x;
    if (i < NN) rowstart[i] = part[i] + bsum[blockIdx.x];
    if (i == 0) rowstart[NN] = NE;
}

// zflag[n]=1 iff node needs hidsum zero-init (deg0 or receives atomics)
__global__ void mark_zero(const int* __restrict__ rowstart,
                          unsigned char* __restrict__ zflag) {
    int n = blockIdx.x * 256 + threadIdx.x;
    if (n >= NN) return;
    int b = rowstart[n], e = rowstart[n + 1];
    bool interior = (b < e) && (b % EPB != 0) && (e % EPB != 0)
                    && ((b / EPB) == ((e - 1) / EPB));
    zflag[n] = interior ? 0 : 1;
}

// scatter ONLY the 4-byte permutation index
__global__ void csr_scatter_perm(const int* __restrict__ dst,
                                 const int* __restrict__ rowstart,
                                 int* __restrict__ cursor,
                                 int* __restrict__ eperm) {
    int e = blockIdx.x * blockDim.x + threadIdx.x;
    if (e < NE) {
        int d = dst[e];
        int pos = atomicAdd(&cursor[d], 1);
        eperm[rowstart[d] + pos] = e;
    }
}

// j-coalesced gather of src/dst/ef via eperm; coalesced writes
__global__ void gather_edges(const int* __restrict__ eperm,
                             const int* __restrict__ src,
                             const int* __restrict__ dst,
                             const float* __restrict__ ef,
                             int* __restrict__ srcs,
                             int* __restrict__ dsts,
                             f16* __restrict__ efs) {
    int j = blockIdx.x * blockDim.x + threadIdx.x;
    if (j >= NE) return;
    int e = eperm[j];
    srcs[j] = src[e];
    dsts[j] = dst[e];
    const float* p = ef + (size_t)e * ED;          // 80 B, 16-aligned
    f16* out = efs + (size_t)j * ED;               // 40 B, 8-aligned
    #pragma unroll
    for (int q = 0; q < 5; ++q) {
        float4 v = *(const float4*)(p + q * 4);
        union { f16 h[4]; uint2 u; } pk;
        pk.h[0] = (f16)v.x; pk.h[1] = (f16)v.y;
        pk.h[2] = (f16)v.z; pk.h[3] = (f16)v.w;
        *(uint2*)(out + q * 4) = pk.u;
    }
}

// ---------------------------------------------------------------------------
// GEMM2 device fn: D[outcol 0..255][node 0..63] = W2s(frag-major) x xlds
// ---------------------------------------------------------------------------
__device__ __forceinline__ void gemm2_store(const f16* xlds,
                                            const f16* __restrict__ W2s_l,
                                            f16* __restrict__ hs,
                                            f16* __restrict__ hd,
                                            int n0, int wave, int lane) {
    int g = lane >> 4, r15 = lane & 15;
    f16x8 B2[4][4];
    #pragma unroll
    for (int nf = 0; nf < 4; ++nf) {
        int row = nf * 16 + r15;
        #pragma unroll
        for (int kc = 0; kc < 4; ++kc)
            B2[nf][kc] = *(const f16x8*)((const char*)xlds + swz(row, kc * 64 + g * 16));
    }
    f16* outb = (wave < 2) ? hs : hd;
    int colw = (wave & 1) * 64;
    #pragma unroll
    for (int mf = 0; mf < 4; ++mf) {
        f16x8 A2[4];
        #pragma unroll
        for (int kc = 0; kc < 4; ++kc)
            A2[kc] = *(const f16x8*)&W2s_l[(size_t)(((wave * 4 + mf) * 4 + kc) * 64 + lane) * 8];
        #pragma unroll
        for (int nf = 0; nf < 4; ++nf) {
            f32x4 acc = {0.f, 0.f, 0.f, 0.f};
            #pragma unroll
            for (int kc = 0; kc < 4; ++kc)
                acc = __builtin_amdgcn_mfma_f32_16x16x32_f16(A2[kc], B2[nf][kc], acc, 0, 0, 0);
            int node = n0 + nf * 16 + r15;
            if (node < NN) {
                union { f16 q[4]; uint2 u; } pk;
                pk.q[0] = (f16)acc[0]; pk.q[1] = (f16)acc[1];
                pk.q[2] = (f16)acc[2]; pk.q[3] = (f16)acc[3];
                *(uint2*)&outb[(size_t)node * H + colw + mf * 16 + g * 4] = pk.u;
            }
        }
    }
}

// ---------------------------------------------------------------------------
// Fused encode + msg_pre (64-node tiles); swapped-operand encode GEMM.
// ---------------------------------------------------------------------------
__global__ void __launch_bounds__(256)
encode_pre_mfma(const float* __restrict__ nf,
                const f16* __restrict__ Wenc,
                const float* __restrict__ neb,
                const unsigned char* __restrict__ zflag,
                const f16* __restrict__ W2s_l0,
                f16* __restrict__ hf,
                f16* __restrict__ hs, f16* __restrict__ hd,
                f16* __restrict__ hidsum) {
    __shared__ f16 xlds[64 * 128];
    int t = threadIdx.x;
    int wave = t >> 6, lane = t & 63;
    int g = lane >> 4, r15 = lane & 15;
    int n0 = blockIdx.x * 64;

    // ---- stage nf as f16 pairs: 46 dword writes/row (cols 0..91, 91 pad 0) ----
    for (int i = t; i < 64 * 46; i += 256) {
        int row = i / 46, c2 = i % 46;
        int col = c2 * 2;
        int n = n0 + row;
        float v0 = 0.f, v1 = 0.f;
        if (n < NN) {
            const float* rp = nf + (size_t)n * ND;
            v0 = rp[col];
            v1 = (col + 1 < ND) ? rp[col + 1] : 0.f;
        }
        union { f16 q[2]; unsigned u; } pk;
        pk.q[0] = (f16)v0; pk.q[1] = (f16)v1;
        *(unsigned*)((char*)xlds + swz(row, col * 2)) = pk.u;
    }
    // ---- zero pad cols 92..127 (dword writes) ----
    for (int i = t; i < 64 * 18; i += 256) {
        int row = i / 18, c2 = 46 + i % 18;        // cols 92..126 step 2
        *(unsigned*)((char*)xlds + swz(row, c2 * 4)) = 0u;
    }
    __syncthreads();

    int lrow = wave * 16 + r15;
    f16x8 A[3];
    #pragma unroll
    for (int kc = 0; kc < 3; ++kc)
        A[kc] = *(const f16x8*)((const char*)xlds + swz(lrow, kc * 64 + g * 16));

    f32x4 acc1[8];
    #pragma unroll
    for (int cf = 0; cf < 8; ++cf) acc1[cf] = (f32x4){0.f, 0.f, 0.f, 0.f};
    #pragma unroll
    for (int cf = 0; cf < 8; ++cf) {
        #pragma unroll
        for (int kc = 0; kc < 3; ++kc) {
            f16x8 b = *(const f16x8*)&Wenc[(size_t)((cf * 3 + kc) * 64 + lane) * 8];
            acc1[cf] = __builtin_amdgcn_mfma_f32_16x16x32_f16(b, A[kc], acc1[cf], 0, 0, 0);
        }
    }
    __syncthreads();

    // h = acc + neb -> xlds (packed: node=r15, channels cf*16+g*4..+3)
    #pragma unroll
    for (int cf = 0; cf < 8; ++cf) {
        int m0 = cf * 16 + g * 4;
        float4 nb4 = *(const float4*)&neb[m0];
        union { f16 q[4]; uint2 u; } pk;
        pk.q[0] = (f16)(acc1[cf][0] + nb4.x);
        pk.q[1] = (f16)(acc1[cf][1] + nb4.y);
        pk.q[2] = (f16)(acc1[cf][2] + nb4.z);
        pk.q[3] = (f16)(acc1[cf][3] + nb4.w);
        *(uint2*)((char*)xlds + swz(lrow, m0 * 2)) = pk.u;
    }
    __syncthreads();

    for (int i = t; i < 64 * 32; i += 256) {
        int row = i >> 5, c4 = i & 31;
        int n = n0 + row;
        if (n < NN) {
            uint2 v = *(const uint2*)((const char*)xlds + swz(row, c4 * 8));
            *(uint2*)&hf[(size_t)n * H + c4 * 4] = v;
            if (zflag[n]) *(uint2*)&hidsum[(size_t)n * H + c4 * 4] = make_uint2(0u, 0u);
        }
    }
    gemm2_store(xlds, W2s_l0, hs, hd, n0, wave, lane);
}

// ---------------------------------------------------------------------------
// flush helpers (thread owns channel pair 2t,2t+1)
// ---------------------------------------------------------------------------
__device__ __forceinline__ void flush_store2(f16* __restrict__ hidsum,
                                             int d, int c2, float a, float b) {
    union { f16 q[2]; unsigned u; } pk;
    pk.q[0] = (f16)a; pk.q[1] = (f16)b;
    *(unsigned*)&hidsum[(size_t)d * H + 2 * c2] = pk.u;
}

__device__ __forceinline__ void flush_atomic2(f16* __restrict__ hidsum,
                                              int d, int c2, float a, float b) {
    unsigned* p = (unsigned*)&hidsum[(size_t)d * H + 2 * c2];
    unsigned old = *p;
    while (true) {
        union { f16 q[2]; unsigned u; } cur, nw;
        cur.u = old;
        nw.q[0] = (f16)((float)cur.q[0] + a);
        nw.q[1] = (f16)((float)cur.q[1] + b);
        unsigned prev = atomicCAS(p, old, nw.u);
        if (prev == old) break;
        old = prev;
    }
}

// ---------------------------------------------------------------------------
// Edge-parallel segmented aggregation; 1 wave/block, 2 channels per thread.
// ---------------------------------------------------------------------------
__global__ void __launch_bounds__(64)
aggregate_edges(const int* __restrict__ srcs,
                const int* __restrict__ dsts,
                const f16* __restrict__ efs,
                const f16* __restrict__ hs,
                const f16* __restrict__ hd,
                const f16x2* __restrict__ wecp_l,
                const float* __restrict__ bec_l,
                f16* __restrict__ hidsum) {
    int t = threadIdx.x;                           // 0..63 -> channels 2t,2t+1
    size_t j0 = (size_t)blockIdx.x * EPB;
    __shared__ f16 efs_lds[EPB * ED];              // 1280 B raw
    __shared__ int sd[2 * EPB];
    {
        const uint4* srcp = (const uint4*)(efs + j0 * ED);
        uint4* dstp = (uint4*)efs_lds;
        for (int i = t; i < 80; i += 64) dstp[i] = srcp[i];
        if (t < EPB) { sd[t] = srcs[j0 + t]; sd[EPB + t] = dsts[j0 + t]; }
    }
    __syncthreads();
    f16x2 wa[ED / 2], wb[ED / 2];
    #pragma unroll
    for (int k2 = 0; k2 < ED / 2; ++k2) {
        wa[k2] = wecp_l[k2 * H + 2 * t];
        wb[k2] = wecp_l[k2 * H + 2 * t + 1];
    }
    float beca = bec_l[2 * t], becb = bec_l[2 * t + 1];
    f16x2 hv[EPB];
    #pragma unroll
    for (int jj = 0; jj < EPB; ++jj) {
        int s = __builtin_amdgcn_readfirstlane(sd[jj]);
        int d = __builtin_amdgcn_readfirstlane(sd[EPB + jj]);
        f16x2 a = *(const f16x2*)&hs[(size_t)s * H + 2 * t];
        f16x2 b = *(const f16x2*)&hd[(size_t)d * H + 2 * t];
        hv[jj] = a + b;                            // v_pk_add_f16
    }
    int dcur = __builtin_amdgcn_readfirstlane(sd[EPB]);
    float acca = 0.f, accb = 0.f;
    int nflush = 0;
    #pragma unroll
    for (int jj = 0; jj < EPB; ++jj) {
        int d = __builtin_amdgcn_readfirstlane(sd[EPB + jj]);
        if (d != dcur) {
            if (nflush == 0) flush_atomic2(hidsum, dcur, t, acca, accb);
            else             flush_store2(hidsum, dcur, t, acca, accb);
            dcur = d; acca = 0.f; accb = 0.f; ++nflush;
        }
        float va = (float)hv[jj][0] + beca;
        float vb = (float)hv[jj][1] + becb;
        const f16x2* ef2 = (const f16x2*)&efs_lds[jj * ED];
        #pragma unroll
        for (int k2 = 0; k2 < ED / 2; ++k2) {
            va = __builtin_amdgcn_fdot2(ef2[k2], wa[k2], va, false);
            vb = __builtin_amdgcn_fdot2(ef2[k2], wb[k2], vb, false);
        }
        acca += fmaxf(va, 0.f);
        accb += fmaxf(vb, 0.f);
    }
    flush_atomic2(hidsum, dcur, t, acca, accb);
}

// ---------------------------------------------------------------------------
// MFMA fused update (64 nodes / 256 threads), swapped-operand GEMM1:
// lane owns node=r15, channels cf*16+g*4..+3 -> packed epilogue.
// last: fused pool (segment sum/max -> hg atomics), no hf write, no GEMM2.
// ---------------------------------------------------------------------------
__global__ void __launch_bounds__(256)
update_pre_mfma(f16* __restrict__ hf,
                f16* __restrict__ hidsum,
                const int* __restrict__ degv,
                const unsigned char* __restrict__ zflag,
                const int* __restrict__ batch,
                const f16* __restrict__ W1s_l,   // frag-major [64][64][8]
                const float* __restrict__ b2u_l,
                const float* __restrict__ updbl,
                const float* __restrict__ lng_l,
                const float* __restrict__ lnb_l,
                const f16* __restrict__ W2s_next,
                f16* __restrict__ hs, f16* __restrict__ hd,
                float* __restrict__ hg_sum, unsigned* __restrict__ hg_maxe,
                int last) {
    __shared__ f16 xlds[64 * 128];
    __shared__ int gbs[64];
    int t = threadIdx.x;
    int wave = t >> 6, lane = t & 63;
    int g = lane >> 4, r15 = lane & 15;
    int n0 = blockIdx.x * 64;

    // ---- A fragments kc4..7 direct from f16 hidsum (coalesced f16x8) ----
    int arow = n0 + wave * 16 + r15;
    bool av = arow < NN;
    f16x8 zero8;
    for (int i = 0; i < 8; ++i) zero8[i] = (f16)0.f;
    f16x8 A1[8];
    #pragma unroll
    for (int kc = 4; kc < 8; ++kc) {
        A1[kc] = av ? *(const f16x8*)&hidsum[(size_t)arow * H + (kc & 3) * 32 + g * 8]
                    : zero8;
    }

    // ---- P1: coalesced stage of hf tile into swizzled LDS ----
    for (int i = t; i < 64 * 32; i += 256) {
        int row = i >> 5, c4 = i & 31;
        int n = n0 + row;
        uint2 v = make_uint2(0u, 0u);
        if (n < NN) v = *(const uint2*)&hf[(size_t)n * H + c4 * 4];
        *(uint2*)((char*)xlds + swz(row, c4 * 8)) = v;
    }
    if (last && t < 64) {
        int n = n0 + t;
        gbs[t] = (n < NN) ? batch[n] : -1;
    }
    __syncthreads();

    // ---- A fragments kc0..3 from xlds ----
    int lrow = wave * 16 + r15;
    #pragma unroll
    for (int kc = 0; kc < 4; ++kc)
        A1[kc] = *(const f16x8*)((const char*)xlds + swz(lrow, kc * 64 + g * 16));

    // ---- GEMM1 swapped: acc1[cf][r] = channel cf*16+g*4+r of node r15 ----
    f32x4 acc1[8];
    #pragma unroll
    for (int cf = 0; cf < 8; ++cf) acc1[cf] = (f32x4){0.f, 0.f, 0.f, 0.f};
    #pragma unroll
    for (int cf = 0; cf < 8; ++cf) {
        #pragma unroll
        for (int kc = 0; kc < 8; ++kc) {
            f16x8 b = *(const f16x8*)&W1s_l[(size_t)((cf * 8 + kc) * 64 + lane) * 8];
            acc1[cf] = __builtin_amdgcn_mfma_f32_16x16x32_f16(b, A1[kc], acc1[cf], 0, 0, 0);
        }
    }

    // ---- packed epilogue: one node per lane ----
    int node = n0 + lrow;
    bool nv = node < NN;
    float degf = nv ? (float)degv[node] : 0.f;
    float x[8][4];
    float s1 = 0.f, s2 = 0.f;
    #pragma unroll
    for (int cf = 0; cf < 8; ++cf) {
        int m0 = cf * 16 + g * 4;
        float4 ub4 = *(const float4*)&updbl[m0];
        float4 b24 = *(const float4*)&b2u_l[m0];
        union { f16 q[4]; uint2 u; } hres;
        hres.u = *(const uint2*)((const char*)xlds + swz(lrow, m0 * 2));
        const float* ubp = (const float*)&ub4;
        const float* b2p = (const float*)&b24;
        #pragma unroll
        for (int r = 0; r < 4; ++r) {
            float xr = (float)hres.q[r]
                     + fmaxf(acc1[cf][r] + ubp[r] + degf * b2p[r], 0.f);
            x[cf][r] = xr;
            s1 += xr; s2 += xr * xr;
        }
    }
    s1 += __shfl_xor(s1, 16); s2 += __shfl_xor(s2, 16);
    s1 += __shfl_xor(s1, 32); s2 += __shfl_xor(s2, 32);
    float mu  = s1 * (1.0f / H);
    float var = s2 * (1.0f / H) - mu * mu;
    float inv = rsqrtf(var + EPSF);
    #pragma unroll
    for (int cf = 0; cf < 8; ++cf) {
        int m0 = cf * 16 + g * 4;
        float4 g4  = *(const float4*)&lng_l[m0];
        float4 bl4 = *(const float4*)&lnb_l[m0];
        const float* gp = (const float*)&g4;
        const float* bp = (const float*)&bl4;
        union { f16 q[4]; uint2 u; } pk;
        #pragma unroll
        for (int r = 0; r < 4; ++r)
            pk.q[r] = (f16)((x[cf][r] - mu) * inv * gp[r] + bp[r]);
        *(uint2*)((char*)xlds + swz(lrow, m0 * 2)) = pk.u;
    }
    __syncthreads();

    if (last) {
        // ---- fused pool: segment sum/max over sorted batch ids ----
        int c = t & 127, q = t >> 7;               // q: rows 0..31 / 32..63
        float s = 0.f, mx = -INFINITY;
        int gcur = -1;
        for (int r = 0; r < 32; ++r) {
            int row = q * 32 + r;
            if (n0 + row >= NN) break;
            int gb = gbs[row];
            if (gb != gcur) {
                if (gcur >= 0) {
                    atomicAdd(&hg_sum[(size_t)gcur * H + c], s);
                    atomicMax(&hg_maxe[(size_t)gcur * H + c], fenc(mx));
                }
                gcur = gb; s = 0.f; mx = -INFINITY;
            }
            float v = (float)*(const f16*)((const char*)xlds + swz(row, c * 2));
            s += v; mx = fmaxf(mx, v);
        }
        if (gcur >= 0) {
            atomicAdd(&hg_sum[(size_t)gcur * H + c], s);
            atomicMax(&hg_maxe[(size_t)gcur * H + c], fenc(mx));
        }
        return;
    }

    // ---- coalesced hf write-back (+ flagged hidsum zero) ----
    for (int i = t; i < 64 * 32; i += 256) {
        int row = i >> 5, c4 = i & 31;
        int n = n0 + row;
        if (n < NN) {
            uint2 v = *(const uint2*)((const char*)xlds + swz(row, c4 * 8));
            *(uint2*)&hf[(size_t)n * H + c4 * 4] = v;
            if (zflag[n]) *(uint2*)&hidsum[(size_t)n * H + c4 * 4] = make_uint2(0u, 0u);
        }
    }
    gemm2_store(xlds, W2s_next, hs, hd, n0, wave, lane);
}

// ---------------------------------------------------------------------------
// readout MLP; computes mean from hg_sum/(cnt+1), decodes max
// ---------------------------------------------------------------------------
__global__ void __launch_bounds__(128)
readout(const float* __restrict__ hg_sum,
        const unsigned* __restrict__ hg_maxe,
        const int* __restrict__ batch,
        const float* __restrict__ W1, const float* __restrict__ b1,
        const float* __restrict__ W2, const float* __restrict__ b2,
        const float* __restrict__ W3, const float* __restrict__ b3,
        float* __restrict__ out) {
    int g = blockIdx.x, t = threadIdx.x;
    __shared__ float xin[2 * H];
    __shared__ float x1[H];
    __shared__ float x2[H / 2];
    int lo = 0, hi = NN;
    while (lo < hi) { int mid = (lo + hi) >> 1; if (batch[mid] < g) lo = mid + 1; else hi = mid; }
    int start = lo;
    hi = NN;
    while (lo < hi) { int mid = (lo + hi) >> 1; if (batch[mid] < g + 1) lo = mid + 1; else hi = mid; }
    float denom = (float)(lo - start) + 1.0f;
    xin[t]     = hg_sum[(size_t)g * H + t] / denom;
    xin[H + t] = fdec(hg_maxe[(size_t)g * H + t]);
    __syncthreads();
    float acc = b1[t];
    for (int k = 0; k < 2 * H; ++k) acc += xin[k] * W1[k * H + t];
    x1[t] = fmaxf(acc, 0.f);
    __syncthreads();
    if (t < 64) {
        float a2 = b2[t];
        for (int k = 0; k < H; ++k) a2 += x1[k] * W2[k * 64 + t];
        x2[t] = fmaxf(a2, 0.f);
    }
    __syncthreads();
    if (t < 64) {
        float v = x2[t] * W3[t];
        #pragma unroll
        for (int off = 32; off >= 1; off >>= 1) v += __shfl_xor(v, off, 64);
        if (t == 0) out[g] = v + b3[0];
    }
}

// ---------------------------------------------------------------------------
extern "C" void kernel_launch(void* const* d_in, const int* in_sizes, int n_in,
                              void* d_out, int out_size, void* d_ws, size_t ws_size,
                              hipStream_t stream) {
    const float* node_feats = (const float*)d_in[0];
    const int*   edge_index = (const int*)d_in[1];
    const float* edge_feats = (const float*)d_in[2];
    const int*   batch      = (const int*)d_in[3];
    const float* ne_W  = (const float*)d_in[4];
    const float* ne_b  = (const float*)d_in[5];
    const float* ee_W  = (const float*)d_in[6];
    const float* ee_b  = (const float*)d_in[7];
    const float* msgW1 = (const float*)d_in[8];
    const float* msgb1 = (const float*)d_in[9];
    const float* msgW2 = (const float*)d_in[10];
    const float* msgb2 = (const float*)d_in[11];
    const float* updW  = (const float*)d_in[12];
    const float* updb  = (const float*)d_in[13];
    const float* lng   = (const float*)d_in[14];
    const float* lnb   = (const float*)d_in[15];
    const float* roW1  = (const float*)d_in[16];
    const float* rob1  = (const float*)d_in[17];
    const float* roW2  = (const float*)d_in[18];
    const float* rob2  = (const float*)d_in[19];
    const float* roW3  = (const float*)d_in[20];
    const float* rob3  = (const float*)d_in[21];

    const int* src = edge_index;            // row 0
    const int* dst = edge_index + NE;       // row 1

    char* ws = (char*)d_ws;
    f16*   hf     = (f16*)ws;   ws += (size_t)NN * H * 2;
    f16*   hidsum = (f16*)ws;   ws += (size_t)NN * H * 2;
    f16*   hs     = (f16*)ws;   ws += (size_t)NN * H * 2;
    f16*   hd     = (f16*)ws;   ws += (size_t)NN * H * 2;
    f16*   efs    = (f16*)ws;   ws += (size_t)NE * ED * 2;
    int* srcs     = (int*)ws; ws += (size_t)NE * 4;
    int* dsts     = (int*)ws; ws += (size_t)NE * 4;
    int* eperm    = (int*)ws; ws += (size_t)NE * 4;
    int* rowstart = (int*)ws; ws += (size_t)(NN + 4) * 4;
    int* deg      = (int*)ws; ws += (size_t)NN * 4;     // reused as cursor; ends = degree
    int* part     = (int*)ws; ws += (size_t)NN * 4;
    int* bsum     = (int*)ws; ws += (size_t)256 * 4;
    unsigned char* zflag = (unsigned char*)ws; ws += ((size_t)NN + 15) / 16 * 16;
    float* Wec = (float*)ws; ws += (size_t)NL * ED * H * 4;
    float* bec = (float*)ws; ws += (size_t)NL * H * 4;
    f16x2* wecp = (f16x2*)ws; ws += (size_t)NL * (ED / 2) * H * 4;
    float* W2u = (float*)ws; ws += (size_t)NL * H * H * 4;
    float* b2u = (float*)ws; ws += (size_t)NL * H * 4;
    f16* W1s = (f16*)ws; ws += (size_t)NL * 64 * 512 * 2;
    f16* W2s = (f16*)ws; ws += (size_t)NL * 64 * 512 * 2;
    f16* Wenc = (f16*)ws; ws += (size_t)24 * 512 * 2;
    float*    hg_sum  = (float*)ws;    ws += (size_t)NG * H * 4;
    unsigned* hg_maxe = (unsigned*)ws; ws += (size_t)NG * H * 4;

    // --- precompute: folded weights + packed/frag-major f16 weights + CSR ---
    fold_edge_weights<<<dim3(ED + 1, NL), H, 0, stream>>>(ee_W, ee_b, msgW1, msgb1, Wec, bec);
    pack_wec<<<dim3(NL, ED / 2), H, 0, stream>>>(Wec, wecp);
    fold_W2u<<<dim3(H + 1, NL), H, 0, stream>>>(msgW2, msgb2, updW, W2u, b2u);
    make_W1s<<<dim3(NL, 64), 64, 0, stream>>>(updW, W2u, W1s);
    make_W2s<<<dim3(NL, 64), 64, 0, stream>>>(msgW1, W2s);
    make_Wenc<<<24, 64, 0, stream>>>(ne_W, Wenc);

    hipMemsetAsync(deg, 0, (size_t)NN * 4, stream);
    hipMemsetAsync(hg_sum, 0, (size_t)NG * H * 8, stream);   // sum + maxe (adjacent)
    csr_count<<<(NE + 255) / 256, 256, 0, stream>>>(dst, deg);
    scan_p1<<<NSC, 1024, 0, stream>>>(deg, part, bsum);
    scan_p2<<<1, 64, 0, stream>>>(bsum);
    scan_p3<<<NSC, 1024, 0, stream>>>(part, bsum, rowstart);
    mark_zero<<<(NN + 255) / 256, 256, 0, stream>>>(rowstart, zflag);
    hipMemsetAsync(deg, 0, (size_t)NN * 4, stream);
    csr_scatter_perm<<<(NE + 255) / 256, 256, 0, stream>>>(dst, rowstart, deg, eperm);
    gather_edges<<<(NE + 255) / 256, 256, 0, stream>>>(eperm, src, dst, edge_feats,
                                                       srcs, dsts, efs);

    encode_pre_mfma<<<NB64, 256, 0, stream>>>(node_feats, Wenc, ne_b, zflag,
                                              W2s, hf, hs, hd, hidsum);

    // --- layers ---
    for (int l = 0; l < NL; ++l) {
        aggregate_edges<<<NE / EPB, 64, 0, stream>>>(srcs, dsts, efs, hs, hd,
                                                     wecp + (size_t)l * (ED / 2) * H,
                                                     bec + (size_t)l * H, hidsum);
        int nl = (l + 1 < NL) ? (l + 1) : 0;   // safe index; unused when last
        update_pre_mfma<<<NB64, 256, 0, stream>>>(hf, hidsum, deg, zflag, batch,
                                                  W1s + (size_t)l * 64 * 512,
                                                  b2u + (size_t)l * H,
                                                  updb + (size_t)l * H,
                                                  lng + (size_t)l * H, lnb + (size_t)l * H,
                                                  W2s + (size_t)nl * 64 * 512,
                                                  hs, hd, hg_sum, hg_maxe,
                                                  (l == NL - 1) ? 1 : 0);
    }

    readout<<<NG, H, 0, stream>>>(hg_sum, hg_maxe, batch,
                                  roW1, rob1, roW2, rob2, roW3, rob3, (float*)d_out);
}

// Round 17
// 459.600 us; speedup vs baseline: 1.0383x; 1.0383x over previous
//
#include <hip/hip_runtime.h>
#include <hip/hip_fp16.h>
#include <math.h>

#define NN 100000
#define NE 500000
#define NG 128
#define ND 91
#define ED 20
#define H  128
#define NL 3
#define EPSF 1e-5f
#define EPB 32          // edges per block in aggregation
#define NB64 ((NN + 63) / 64)
#define NSC ((NN + 1023) / 1024)

typedef _Float16 f16;
typedef _Float16 f16x2 __attribute__((ext_vector_type(2)));
typedef _Float16 f16x8 __attribute__((ext_vector_type(8)));
typedef float    f32x4 __attribute__((ext_vector_type(4)));

// swizzled LDS byte offset for a [64][128] f16 tile (row stride 256 B)
__device__ __forceinline__ int swz(int row, int colbyte) {
    return (row * 256 + colbyte) ^ ((row & 7) << 4);
}

// order-preserving float<->uint for atomicMax
__device__ __forceinline__ unsigned fenc(float f) {
    unsigned u = __float_as_uint(f);
    return (u & 0x80000000u) ? ~u : (u | 0x80000000u);
}
__device__ __forceinline__ float fdec(unsigned key) {
    unsigned u = (key & 0x80000000u) ? (key & 0x7FFFFFFFu) : ~key;
    return __uint_as_float(u);
}

// ---------------------------------------------------------------------------
// Fold edge-feature path: Wec[l] = ee_W @ msg_W1[l][2H:3H,:]
// ---------------------------------------------------------------------------
__global__ void fold_edge_weights(const float* __restrict__ eeW,
                                  const float* __restrict__ eeb,
                                  const float* __restrict__ msgW1,
                                  const float* __restrict__ msgb1,
                                  float* __restrict__ Wec,
                                  float* __restrict__ bec) {
    int l = blockIdx.y;
    int k = blockIdx.x;                        // 0..ED (ED => bias row)
    int c = threadIdx.x;
    const float* W1e = msgW1 + (size_t)l * 3 * H * H + (size_t)2 * H * H;
    if (k < ED) {
        float acc = 0.f;
        for (int m = 0; m < H; ++m) acc += eeW[k * H + m] * W1e[m * H + c];
        Wec[((size_t)l * ED + k) * H + c] = acc;
    } else {
        float acc = msgb1[l * H + c];
        for (int m = 0; m < H; ++m) acc += eeb[m] * W1e[m * H + c];
        bec[(size_t)l * H + c] = acc;
    }
}

// pack Wec into f16 pairs
__global__ void pack_wec(const float* __restrict__ Wec,
                         f16x2* __restrict__ wecp) {
    int l = blockIdx.x, k2 = blockIdx.y, c = threadIdx.x;
    f16x2 v;
    v[0] = (f16)Wec[((size_t)l * ED + 2 * k2) * H + c];
    v[1] = (f16)Wec[((size_t)l * ED + 2 * k2 + 1) * H + c];
    wecp[((size_t)l * (ED / 2) + k2) * H + c] = v;
}

// ---------------------------------------------------------------------------
// Fold msg_W2 into update weights
// ---------------------------------------------------------------------------
__global__ void fold_W2u(const float* __restrict__ msgW2,
                         const float* __restrict__ msgb2,
                         const float* __restrict__ updW,
                         float* __restrict__ W2u,
                         float* __restrict__ b2u) {
    int l = blockIdx.y;
    int k = blockIdx.x;                        // 0..H (H => bias row)
    int c = threadIdx.x;
    const float* Wbot = updW + (size_t)l * 2 * H * H + (size_t)H * H;
    if (k < H) {
        const float* w2row = msgW2 + (size_t)l * H * H + (size_t)k * H;
        float acc = 0.f;
        for (int m = 0; m < H; ++m) acc += w2row[m] * Wbot[m * H + c];
        W2u[((size_t)l * H + k) * H + c] = acc;
    } else {
        const float* b2 = msgb2 + (size_t)l * H;
        float acc = 0.f;
        for (int m = 0; m < H; ++m) acc += b2[m] * Wbot[m * H + c];
        b2u[(size_t)l * H + c] = acc;
    }
}

// ---------------------------------------------------------------------------
// W1s: fragment-major pre-swizzled GEMM1 weights.
// ---------------------------------------------------------------------------
__global__ void make_W1s(const float* __restrict__ updW,
                         const float* __restrict__ W2u,
                         f16* __restrict__ W1s) {
    int l = blockIdx.x, frag = blockIdx.y, lane = threadIdx.x;  // 64 threads
    int cf = frag >> 3, kc = frag & 7;
    int col = cf * 16 + (lane & 15);
    int k0 = kc * 32 + (lane >> 4) * 8;
    f16* out = W1s + ((size_t)l * 64 + frag) * 512 + lane * 8;
    for (int j = 0; j < 8; ++j) {
        int k = k0 + j;
        float v = (k < H) ? updW[(size_t)l * 2 * H * H + (size_t)k * H + col]
                          : W2u[(size_t)l * H * H + (size_t)(k - H) * H + col];
        out[j] = (f16)v;
    }
}

// ---------------------------------------------------------------------------
// W2s: fragment-major pre-swizzled GEMM2 weights.
// ---------------------------------------------------------------------------
__global__ void make_W2s(const float* __restrict__ msgW1,
                         f16* __restrict__ W2s) {
    int l = blockIdx.x, frag = blockIdx.y, lane = threadIdx.x;  // 64 threads
    int wave = frag >> 4, mf = (frag >> 2) & 3, kc = frag & 3;
    int oc = wave * 64 + mf * 16 + (lane & 15);
    int k0 = kc * 32 + (lane >> 4) * 8;
    const float* W1 = msgW1 + (size_t)l * 3 * H * H;
    f16* out = W2s + ((size_t)l * 64 + frag) * 512 + lane * 8;
    for (int j = 0; j < 8; ++j) {
        int k = k0 + j;
        float v = W1[(size_t)((oc < H ? 0 : H) + k) * H + (oc & (H - 1))];
        out[j] = (f16)v;
    }
}

// ---------------------------------------------------------------------------
// Wenc: fragment-major encode weights (K padded 96)
// ---------------------------------------------------------------------------
__global__ void make_Wenc(const float* __restrict__ neW,
                          f16* __restrict__ Wenc) {
    int frag = blockIdx.x, lane = threadIdx.x;  // 24 frags, 64 threads
    int cf = frag / 3, kc = frag % 3;
    int col = cf * 16 + (lane & 15);
    int k0 = kc * 32 + (lane >> 4) * 8;
    f16* out = Wenc + (size_t)frag * 512 + lane * 8;
    for (int j = 0; j < 8; ++j) {
        int k = k0 + j;
        out[j] = (k < ND) ? (f16)neW[(size_t)k * H + col] : (f16)0.f;
    }
}

// ---------------------------------------------------------------------------
// CSR build over dst
// ---------------------------------------------------------------------------
__global__ void csr_count(const int* __restrict__ dst, int* __restrict__ deg) {
    int e = blockIdx.x * blockDim.x + threadIdx.x;
    if (e < NE) atomicAdd(&deg[dst[e]], 1);
}

__global__ void scan_p1(const int* __restrict__ deg,
                        int* __restrict__ part, int* __restrict__ bsum) {
    __shared__ int ws[16];
    int t = threadIdx.x, lane = t & 63, w = t >> 6;
    int i = blockIdx.x * 1024 + t;
    int v = (i < NN) ? deg[i] : 0;
    int inc = v;
    #pragma unroll
    for (int off = 1; off < 64; off <<= 1) {
        int u = __shfl_up(inc, off, 64);
        if (lane >= off) inc += u;
    }
    if (lane == 63) ws[w] = inc;
    __syncthreads();
    if (t == 0) {
        int run = 0;
        #pragma unroll
        for (int q = 0; q < 16; ++q) { int tmp = ws[q]; ws[q] = run; run += tmp; }
        bsum[blockIdx.x] = run;
    }
    __syncthreads();
    if (i < NN) part[i] = ws[w] + inc - v;
}

__global__ void scan_p2(int* __restrict__ bsum) {
    if (threadIdx.x == 0) {
        int run = 0;
        for (int q = 0; q < NSC; ++q) { int tmp = bsum[q]; bsum[q] = run; run += tmp; }
    }
}

__global__ void scan_p3(const int* __restrict__ part, const int* __restrict__ bsum,
                        int* __restrict__ rowstart) {
    int i = blockIdx.x * 1024 + threadIdx.x;
    if (i < NN) rowstart[i] = part[i] + bsum[blockIdx.x];
    if (i == 0) rowstart[NN] = NE;
}

// zflag[n]=1 iff node needs hidsum zero-init (deg0 or receives atomics)
__global__ void mark_zero(const int* __restrict__ rowstart,
                          unsigned char* __restrict__ zflag) {
    int n = blockIdx.x * 256 + threadIdx.x;
    if (n >= NN) return;
    int b = rowstart[n], e = rowstart[n + 1];
    bool interior = (b < e) && (b % EPB != 0) && (e % EPB != 0)
                    && ((b / EPB) == ((e - 1) / EPB));
    zflag[n] = interior ? 0 : 1;
}

__global__ void csr_scatter(const int* __restrict__ src,
                            const int* __restrict__ dst,
                            const float* __restrict__ ef,
                            const int* __restrict__ rowstart,
                            int* __restrict__ cursor,
                            int* __restrict__ srcs,
                            int* __restrict__ dsts,
                            f16* __restrict__ efs) {
    int e = blockIdx.x * blockDim.x + threadIdx.x;
    if (e < NE) {
        int d = dst[e];
        int pos = atomicAdd(&cursor[d], 1);
        int j = rowstart[d] + pos;
        srcs[j] = src[e];
        dsts[j] = d;
        const float* p = ef + (size_t)e * ED;
        f16* out = efs + (size_t)j * ED;
        #pragma unroll
        for (int q = 0; q < 5; ++q) {
            float4 v = *(const float4*)(p + q * 4);
            union { f16 h[4]; uint2 u; } pk;
            pk.h[0] = (f16)v.x; pk.h[1] = (f16)v.y;
            pk.h[2] = (f16)v.z; pk.h[3] = (f16)v.w;
            *(uint2*)(out + q * 4) = pk.u;
        }
    }
}

// ---------------------------------------------------------------------------
// GEMM2 device fn: D[outcol 0..255][node 0..63] = W2s(frag-major) x xlds
// ---------------------------------------------------------------------------
__device__ __forceinline__ void gemm2_store(const f16* xlds,
                                            const f16* __restrict__ W2s_l,
                                            f16* __restrict__ hs,
                                            f16* __restrict__ hd,
                                            int n0, int wave, int lane) {
    int g = lane >> 4, r15 = lane & 15;
    f16x8 B2[4][4];
    #pragma unroll
    for (int nf = 0; nf < 4; ++nf) {
        int row = nf * 16 + r15;
        #pragma unroll
        for (int kc = 0; kc < 4; ++kc)
            B2[nf][kc] = *(const f16x8*)((const char*)xlds + swz(row, kc * 64 + g * 16));
    }
    f16* outb = (wave < 2) ? hs : hd;
    int colw = (wave & 1) * 64;
    #pragma unroll
    for (int mf = 0; mf < 4; ++mf) {
        f16x8 A2[4];
        #pragma unroll
        for (int kc = 0; kc < 4; ++kc)
            A2[kc] = *(const f16x8*)&W2s_l[(size_t)(((wave * 4 + mf) * 4 + kc) * 64 + lane) * 8];
        #pragma unroll
        for (int nf = 0; nf < 4; ++nf) {
            f32x4 acc = {0.f, 0.f, 0.f, 0.f};
            #pragma unroll
            for (int kc = 0; kc < 4; ++kc)
                acc = __builtin_amdgcn_mfma_f32_16x16x32_f16(A2[kc], B2[nf][kc], acc, 0, 0, 0);
            int node = n0 + nf * 16 + r15;
            if (node < NN) {
                union { f16 q[4]; uint2 u; } pk;
                pk.q[0] = (f16)acc[0]; pk.q[1] = (f16)acc[1];
                pk.q[2] = (f16)acc[2]; pk.q[3] = (f16)acc[3];
                *(uint2*)&outb[(size_t)node * H + colw + mf * 16 + g * 4] = pk.u;
            }
        }
    }
}

// ---------------------------------------------------------------------------
// Fused encode + msg_pre (64-node tiles); swapped-operand encode GEMM.
// ---------------------------------------------------------------------------
__global__ void __launch_bounds__(256)
encode_pre_mfma(const float* __restrict__ nf,
                const f16* __restrict__ Wenc,
                const float* __restrict__ neb,
                const unsigned char* __restrict__ zflag,
                const f16* __restrict__ W2s_l0,
                f16* __restrict__ hf,
                f16* __restrict__ hs, f16* __restrict__ hd,
                f16* __restrict__ hidsum) {
    __shared__ f16 xlds[64 * 128];
    int t = threadIdx.x;
    int wave = t >> 6, lane = t & 63;
    int g = lane >> 4, r15 = lane & 15;
    int n0 = blockIdx.x * 64;

    // ---- stage nf as f16 pairs: 46 dword writes/row (cols 0..91, 91 pad 0) ----
    for (int i = t; i < 64 * 46; i += 256) {
        int row = i / 46, c2 = i % 46;
        int col = c2 * 2;
        int n = n0 + row;
        float v0 = 0.f, v1 = 0.f;
        if (n < NN) {
            const float* rp = nf + (size_t)n * ND;
            v0 = rp[col];
            v1 = (col + 1 < ND) ? rp[col + 1] : 0.f;
        }
        union { f16 q[2]; unsigned u; } pk;
        pk.q[0] = (f16)v0; pk.q[1] = (f16)v1;
        *(unsigned*)((char*)xlds + swz(row, col * 2)) = pk.u;
    }
    // ---- zero pad cols 92..127 (dword writes) ----
    for (int i = t; i < 64 * 18; i += 256) {
        int row = i / 18, c2 = 46 + i % 18;        // cols 92..126 step 2
        *(unsigned*)((char*)xlds + swz(row, c2 * 4)) = 0u;
    }
    __syncthreads();

    int lrow = wave * 16 + r15;
    f16x8 A[3];
    #pragma unroll
    for (int kc = 0; kc < 3; ++kc)
        A[kc] = *(const f16x8*)((const char*)xlds + swz(lrow, kc * 64 + g * 16));

    f32x4 acc1[8];
    #pragma unroll
    for (int cf = 0; cf < 8; ++cf) acc1[cf] = (f32x4){0.f, 0.f, 0.f, 0.f};
    #pragma unroll
    for (int cf = 0; cf < 8; ++cf) {
        #pragma unroll
        for (int kc = 0; kc < 3; ++kc) {
            f16x8 b = *(const f16x8*)&Wenc[(size_t)((cf * 3 + kc) * 64 + lane) * 8];
            acc1[cf] = __builtin_amdgcn_mfma_f32_16x16x32_f16(b, A[kc], acc1[cf], 0, 0, 0);
        }
    }
    __syncthreads();

    // h = acc + neb -> xlds (packed: node=r15, channels cf*16+g*4..+3)
    #pragma unroll
    for (int cf = 0; cf < 8; ++cf) {
        int m0 = cf * 16 + g * 4;
        float4 nb4 = *(const float4*)&neb[m0];
        union { f16 q[4]; uint2 u; } pk;
        pk.q[0] = (f16)(acc1[cf][0] + nb4.x);
        pk.q[1] = (f16)(acc1[cf][1] + nb4.y);
        pk.q[2] = (f16)(acc1[cf][2] + nb4.z);
        pk.q[3] = (f16)(acc1[cf][3] + nb4.w);
        *(uint2*)((char*)xlds + swz(lrow, m0 * 2)) = pk.u;
    }
    __syncthreads();

    for (int i = t; i < 64 * 32; i += 256) {
        int row = i >> 5, c4 = i & 31;
        int n = n0 + row;
        if (n < NN) {
            uint2 v = *(const uint2*)((const char*)xlds + swz(row, c4 * 8));
            *(uint2*)&hf[(size_t)n * H + c4 * 4] = v;
            if (zflag[n]) *(uint2*)&hidsum[(size_t)n * H + c4 * 4] = make_uint2(0u, 0u);
        }
    }
    gemm2_store(xlds, W2s_l0, hs, hd, n0, wave, lane);
}

// ---------------------------------------------------------------------------
// flush helpers (thread owns channel pair 2t,2t+1)
// ---------------------------------------------------------------------------
__device__ __forceinline__ void flush_store2(f16* __restrict__ hidsum,
                                             int d, int c2, float a, float b) {
    union { f16 q[2]; unsigned u; } pk;
    pk.q[0] = (f16)a; pk.q[1] = (f16)b;
    *(unsigned*)&hidsum[(size_t)d * H + 2 * c2] = pk.u;
}

__device__ __forceinline__ void flush_atomic2(f16* __restrict__ hidsum,
                                              int d, int c2, float a, float b) {
    unsigned* p = (unsigned*)&hidsum[(size_t)d * H + 2 * c2];
    unsigned old = *p;
    while (true) {
        union { f16 q[2]; unsigned u; } cur, nw;
        cur.u = old;
        nw.q[0] = (f16)((float)cur.q[0] + a);
        nw.q[1] = (f16)((float)cur.q[1] + b);
        unsigned prev = atomicCAS(p, old, nw.u);
        if (prev == old) break;
        old = prev;
    }
}

// ---------------------------------------------------------------------------
// Edge-parallel segmented aggregation; 1 wave/block, 2 channels per thread.
// ---------------------------------------------------------------------------
__global__ void __launch_bounds__(64)
aggregate_edges(const int* __restrict__ srcs,
                const int* __restrict__ dsts,
                const f16* __restrict__ efs,
                const f16* __restrict__ hs,
                const f16* __restrict__ hd,
                const f16x2* __restrict__ wecp_l,
                const float* __restrict__ bec_l,
                f16* __restrict__ hidsum) {
    int t = threadIdx.x;                           // 0..63 -> channels 2t,2t+1
    size_t j0 = (size_t)blockIdx.x * EPB;
    __shared__ f16 efs_lds[EPB * ED];              // 1280 B raw
    __shared__ int sd[2 * EPB];
    {
        const uint4* srcp = (const uint4*)(efs + j0 * ED);
        uint4* dstp = (uint4*)efs_lds;
        for (int i = t; i < 80; i += 64) dstp[i] = srcp[i];
        if (t < EPB) { sd[t] = srcs[j0 + t]; sd[EPB + t] = dsts[j0 + t]; }
    }
    __syncthreads();
    f16x2 wa[ED / 2], wb[ED / 2];
    #pragma unroll
    for (int k2 = 0; k2 < ED / 2; ++k2) {
        wa[k2] = wecp_l[k2 * H + 2 * t];
        wb[k2] = wecp_l[k2 * H + 2 * t + 1];
    }
    float beca = bec_l[2 * t], becb = bec_l[2 * t + 1];
    f16x2 hv[EPB];
    #pragma unroll
    for (int jj = 0; jj < EPB; ++jj) {
        int s = __builtin_amdgcn_readfirstlane(sd[jj]);
        int d = __builtin_amdgcn_readfirstlane(sd[EPB + jj]);
        f16x2 a = *(const f16x2*)&hs[(size_t)s * H + 2 * t];
        f16x2 b = *(const f16x2*)&hd[(size_t)d * H + 2 * t];
        hv[jj] = a + b;                            // v_pk_add_f16
    }
    int dcur = __builtin_amdgcn_readfirstlane(sd[EPB]);
    float acca = 0.f, accb = 0.f;
    int nflush = 0;
    #pragma unroll
    for (int jj = 0; jj < EPB; ++jj) {
        int d = __builtin_amdgcn_readfirstlane(sd[EPB + jj]);
        if (d != dcur) {
            if (nflush == 0) flush_atomic2(hidsum, dcur, t, acca, accb);
            else             flush_store2(hidsum, dcur, t, acca, accb);
            dcur = d; acca = 0.f; accb = 0.f; ++nflush;
        }
        float va = (float)hv[jj][0] + beca;
        float vb = (float)hv[jj][1] + becb;
        const f16x2* ef2 = (const f16x2*)&efs_lds[jj * ED];
        #pragma unroll
        for (int k2 = 0; k2 < ED / 2; ++k2) {
            va = __builtin_amdgcn_fdot2(ef2[k2], wa[k2], va, false);
            vb = __builtin_amdgcn_fdot2(ef2[k2], wb[k2], vb, false);
        }
        acca += fmaxf(va, 0.f);
        accb += fmaxf(vb, 0.f);
    }
    flush_atomic2(hidsum, dcur, t, acca, accb);
}

// ---------------------------------------------------------------------------
// MFMA fused update (64 nodes / 256 threads), swapped-operand GEMM1:
// lane owns node=r15, channels cf*16+g*4..+3 -> packed epilogue.
// last: fused pool (segment sum/max -> hg atomics), no hf write, no GEMM2.
// ---------------------------------------------------------------------------
__global__ void __launch_bounds__(256)
update_pre_mfma(f16* __restrict__ hf,
                f16* __restrict__ hidsum,
                const int* __restrict__ degv,
                const unsigned char* __restrict__ zflag,
                const int* __restrict__ batch,
                const f16* __restrict__ W1s_l,   // frag-major [64][64][8]
                const float* __restrict__ b2u_l,
                const float* __restrict__ updbl,
                const float* __restrict__ lng_l,
                const float* __restrict__ lnb_l,
                const f16* __restrict__ W2s_next,
                f16* __restrict__ hs, f16* __restrict__ hd,
                float* __restrict__ hg_sum, unsigned* __restrict__ hg_maxe,
                int last) {
    __shared__ f16 xlds[64 * 128];
    __shared__ int gbs[64];
    int t = threadIdx.x;
    int wave = t >> 6, lane = t & 63;
    int g = lane >> 4, r15 = lane & 15;
    int n0 = blockIdx.x * 64;

    // ---- A fragments kc4..7 direct from f16 hidsum (coalesced f16x8) ----
    int arow = n0 + wave * 16 + r15;
    bool av = arow < NN;
    f16x8 zero8;
    for (int i = 0; i < 8; ++i) zero8[i] = (f16)0.f;
    f16x8 A1[8];
    #pragma unroll
    for (int kc = 4; kc < 8; ++kc) {
        A1[kc] = av ? *(const f16x8*)&hidsum[(size_t)arow * H + (kc & 3) * 32 + g * 8]
                    : zero8;
    }

    // ---- P1: coalesced stage of hf tile into swizzled LDS ----
    for (int i = t; i < 64 * 32; i += 256) {
        int row = i >> 5, c4 = i & 31;
        int n = n0 + row;
        uint2 v = make_uint2(0u, 0u);
        if (n < NN) v = *(const uint2*)&hf[(size_t)n * H + c4 * 4];
        *(uint2*)((char*)xlds + swz(row, c4 * 8)) = v;
    }
    if (last && t < 64) {
        int n = n0 + t;
        gbs[t] = (n < NN) ? batch[n] : -1;
    }
    __syncthreads();

    // ---- A fragments kc0..3 from xlds ----
    int lrow = wave * 16 + r15;
    #pragma unroll
    for (int kc = 0; kc < 4; ++kc)
        A1[kc] = *(const f16x8*)((const char*)xlds + swz(lrow, kc * 64 + g * 16));

    // ---- GEMM1 swapped: acc1[cf][r] = channel cf*16+g*4+r of node r15 ----
    f32x4 acc1[8];
    #pragma unroll
    for (int cf = 0; cf < 8; ++cf) acc1[cf] = (f32x4){0.f, 0.f, 0.f, 0.f};
    #pragma unroll
    for (int cf = 0; cf < 8; ++cf) {
        #pragma unroll
        for (int kc = 0; kc < 8; ++kc) {
            f16x8 b = *(const f16x8*)&W1s_l[(size_t)((cf * 8 + kc) * 64 + lane) * 8];
            acc1[cf] = __builtin_amdgcn_mfma_f32_16x16x32_f16(b, A1[kc], acc1[cf], 0, 0, 0);
        }
    }

    // ---- packed epilogue: one node per lane ----
    int node = n0 + lrow;
    bool nv = node < NN;
    float degf = nv ? (float)degv[node] : 0.f;
    float x[8][4];
    float s1 = 0.f, s2 = 0.f;
    #pragma unroll
    for (int cf = 0; cf < 8; ++cf) {
        int m0 = cf * 16 + g * 4;
        float4 ub4 = *(const float4*)&updbl[m0];
        float4 b24 = *(const float4*)&b2u_l[m0];
        union { f16 q[4]; uint2 u; } hres;
        hres.u = *(const uint2*)((const char*)xlds + swz(lrow, m0 * 2));
        const float* ubp = (const float*)&ub4;
        const float* b2p = (const float*)&b24;
        #pragma unroll
        for (int r = 0; r < 4; ++r) {
            float xr = (float)hres.q[r]
                     + fmaxf(acc1[cf][r] + ubp[r] + degf * b2p[r], 0.f);
            x[cf][r] = xr;
            s1 += xr; s2 += xr * xr;
        }
    }
    s1 += __shfl_xor(s1, 16); s2 += __shfl_xor(s2, 16);
    s1 += __shfl_xor(s1, 32); s2 += __shfl_xor(s2, 32);
    float mu  = s1 * (1.0f / H);
    float var = s2 * (1.0f / H) - mu * mu;
    float inv = rsqrtf(var + EPSF);
    #pragma unroll
    for (int cf = 0; cf < 8; ++cf) {
        int m0 = cf * 16 + g * 4;
        float4 g4  = *(const float4*)&lng_l[m0];
        float4 bl4 = *(const float4*)&lnb_l[m0];
        const float* gp = (const float*)&g4;
        const float* bp = (const float*)&bl4;
        union { f16 q[4]; uint2 u; } pk;
        #pragma unroll
        for (int r = 0; r < 4; ++r)
            pk.q[r] = (f16)((x[cf][r] - mu) * inv * gp[r] + bp[r]);
        *(uint2*)((char*)xlds + swz(lrow, m0 * 2)) = pk.u;
    }
    __syncthreads();

    if (last) {
        // ---- fused pool: segment sum/max over sorted batch ids ----
        int c = t & 127, q = t >> 7;               // q: rows 0..31 / 32..63
        float s = 0.f, mx = -INFINITY;
        int gcur = -1;
        for (int r = 0; r < 32; ++r) {
            int row = q * 32 + r;
            if (n0 + row >= NN) break;
            int gb = gbs[row];
            if (gb != gcur) {
                if (gcur >= 0) {
                    atomicAdd(&hg_sum[(size_t)gcur * H + c], s);
                    atomicMax(&hg_maxe[(size_t)gcur * H + c], fenc(mx));
                }
                gcur = gb; s = 0.f; mx = -INFINITY;
            }
            float v = (float)*(const f16*)((const char*)xlds + swz(row, c * 2));
            s += v; mx = fmaxf(mx, v);
        }
        if (gcur >= 0) {
            atomicAdd(&hg_sum[(size_t)gcur * H + c], s);
            atomicMax(&hg_maxe[(size_t)gcur * H + c], fenc(mx));
        }
        return;
    }

    // ---- coalesced hf write-back (+ flagged hidsum zero) ----
    for (int i = t; i < 64 * 32; i += 256) {
        int row = i >> 5, c4 = i & 31;
        int n = n0 + row;
        if (n < NN) {
            uint2 v = *(const uint2*)((const char*)xlds + swz(row, c4 * 8));
            *(uint2*)&hf[(size_t)n * H + c4 * 4] = v;
            if (zflag[n]) *(uint2*)&hidsum[(size_t)n * H + c4 * 4] = make_uint2(0u, 0u);
        }
    }
    gemm2_store(xlds, W2s_next, hs, hd, n0, wave, lane);
}

// ---------------------------------------------------------------------------
// readout MLP; computes mean from hg_sum/(cnt+1), decodes max
// ---------------------------------------------------------------------------
__global__ void __launch_bounds__(128)
readout(const float* __restrict__ hg_sum,
        const unsigned* __restrict__ hg_maxe,
        const int* __restrict__ batch,
        const float* __restrict__ W1, const float* __restrict__ b1,
        const float* __restrict__ W2, const float* __restrict__ b2,
        const float* __restrict__ W3, const float* __restrict__ b3,
        float* __restrict__ out) {
    int g = blockIdx.x, t = threadIdx.x;
    __shared__ float xin[2 * H];
    __shared__ float x1[H];
    __shared__ float x2[H / 2];
    int lo = 0, hi = NN;
    while (lo < hi) { int mid = (lo + hi) >> 1; if (batch[mid] < g) lo = mid + 1; else hi = mid; }
    int start = lo;
    hi = NN;
    while (lo < hi) { int mid = (lo + hi) >> 1; if (batch[mid] < g + 1) lo = mid + 1; else hi = mid; }
    float denom = (float)(lo - start) + 1.0f;
    xin[t]     = hg_sum[(size_t)g * H + t] / denom;
    xin[H + t] = fdec(hg_maxe[(size_t)g * H + t]);
    __syncthreads();
    float acc = b1[t];
    for (int k = 0; k < 2 * H; ++k) acc += xin[k] * W1[k * H + t];
    x1[t] = fmaxf(acc, 0.f);
    __syncthreads();
    if (t < 64) {
        float a2 = b2[t];
        for (int k = 0; k < H; ++k) a2 += x1[k] * W2[k * 64 + t];
        x2[t] = fmaxf(a2, 0.f);
    }
    __syncthreads();
    if (t < 64) {
        float v = x2[t] * W3[t];
        #pragma unroll
        for (int off = 32; off >= 1; off >>= 1) v += __shfl_xor(v, off, 64);
        if (t == 0) out[g] = v + b3[0];
    }
}

// ---------------------------------------------------------------------------
extern "C" void kernel_launch(void* const* d_in, const int* in_sizes, int n_in,
                              void* d_out, int out_size, void* d_ws, size_t ws_size,
                              hipStream_t stream) {
    const float* node_feats = (const float*)d_in[0];
    const int*   edge_index = (const int*)d_in[1];
    const float* edge_feats = (const float*)d_in[2];
    const int*   batch      = (const int*)d_in[3];
    const float* ne_W  = (const float*)d_in[4];
    const float* ne_b  = (const float*)d_in[5];
    const float* ee_W  = (const float*)d_in[6];
    const float* ee_b  = (const float*)d_in[7];
    const float* msgW1 = (const float*)d_in[8];
    const float* msgb1 = (const float*)d_in[9];
    const float* msgW2 = (const float*)d_in[10];
    const float* msgb2 = (const float*)d_in[11];
    const float* updW  = (const float*)d_in[12];
    const float* updb  = (const float*)d_in[13];
    const float* lng   = (const float*)d_in[14];
    const float* lnb   = (const float*)d_in[15];
    const float* roW1  = (const float*)d_in[16];
    const float* rob1  = (const float*)d_in[17];
    const float* roW2  = (const float*)d_in[18];
    const float* rob2  = (const float*)d_in[19];
    const float* roW3  = (const float*)d_in[20];
    const float* rob3  = (const float*)d_in[21];

    const int* src = edge_index;            // row 0
    const int* dst = edge_index + NE;       // row 1

    char* ws = (char*)d_ws;
    f16*   hf     = (f16*)ws;   ws += (size_t)NN * H * 2;
    f16*   hidsum = (f16*)ws;   ws += (size_t)NN * H * 2;
    f16*   hs     = (f16*)ws;   ws += (size_t)NN * H * 2;
    f16*   hd     = (f16*)ws;   ws += (size_t)NN * H * 2;
    f16*   efs    = (f16*)ws;   ws += (size_t)NE * ED * 2;
    int* srcs     = (int*)ws; ws += (size_t)NE * 4;
    int* dsts     = (int*)ws; ws += (size_t)NE * 4;
    int* rowstart = (int*)ws; ws += (size_t)(NN + 4) * 4;
    int* deg      = (int*)ws; ws += (size_t)NN * 4;     // reused as cursor; ends = degree
    int* part     = (int*)ws; ws += (size_t)NN * 4;
    int* bsum     = (int*)ws; ws += (size_t)256 * 4;
    unsigned char* zflag = (unsigned char*)ws; ws += ((size_t)NN + 15) / 16 * 16;
    float* Wec = (float*)ws; ws += (size_t)NL * ED * H * 4;
    float* bec = (float*)ws; ws += (size_t)NL * H * 4;
    f16x2* wecp = (f16x2*)ws; ws += (size_t)NL * (ED / 2) * H * 4;
    float* W2u = (float*)ws; ws += (size_t)NL * H * H * 4;
    float* b2u = (float*)ws; ws += (size_t)NL * H * 4;
    f16* W1s = (f16*)ws; ws += (size_t)NL * 64 * 512 * 2;
    f16* W2s = (f16*)ws; ws += (size_t)NL * 64 * 512 * 2;
    f16* Wenc = (f16*)ws; ws += (size_t)24 * 512 * 2;
    float*    hg_sum  = (float*)ws;    ws += (size_t)NG * H * 4;
    unsigned* hg_maxe = (unsigned*)ws; ws += (size_t)NG * H * 4;

    // --- precompute: folded weights + packed/frag-major f16 weights + CSR ---
    fold_edge_weights<<<dim3(ED + 1, NL), H, 0, stream>>>(ee_W, ee_b, msgW1, msgb1, Wec, bec);
    pack_wec<<<dim3(NL, ED / 2), H, 0, stream>>>(Wec, wecp);
    fold_W2u<<<dim3(H + 1, NL), H, 0, stream>>>(msgW2, msgb2, updW, W2u, b2u);
    make_W1s<<<dim3(NL, 64), 64, 0, stream>>>(updW, W2u, W1s);
    make_W2s<<<dim3(NL, 64), 64, 0, stream>>>(msgW1, W2s);
    make_Wenc<<<24, 64, 0, stream>>>(ne_W, Wenc);

    hipMemsetAsync(deg, 0, (size_t)NN * 4, stream);
    hipMemsetAsync(hg_sum, 0, (size_t)NG * H * 8, stream);   // sum + maxe (adjacent)
    csr_count<<<(NE + 255) / 256, 256, 0, stream>>>(dst, deg);
    scan_p1<<<NSC, 1024, 0, stream>>>(deg, part, bsum);
    scan_p2<<<1, 64, 0, stream>>>(bsum);
    scan_p3<<<NSC, 1024, 0, stream>>>(part, bsum, rowstart);
    mark_zero<<<(NN + 255) / 256, 256, 0, stream>>>(rowstart, zflag);
    hipMemsetAsync(deg, 0, (size_t)NN * 4, stream);
    csr_scatter<<<(NE + 255) / 256, 256, 0, stream>>>(src, dst, edge_feats, rowstart,
                                                      deg, srcs, dsts, efs);

    encode_pre_mfma<<<NB64, 256, 0, stream>>>(node_feats, Wenc, ne_b, zflag,
                                              W2s, hf, hs, hd, hidsum);

    // --- layers ---
    for (int l = 0; l < NL; ++l) {
        aggregate_edges<<<NE / EPB, 64, 0, stream>>>(srcs, dsts, efs, hs, hd,
                                                     wecp + (size_t)l * (ED / 2) * H,
                                                     bec + (size_t)l * H, hidsum);
        int nl = (l + 1 < NL) ? (l + 1) : 0;   // safe index; unused when last
        update_pre_mfma<<<NB64, 256, 0, stream>>>(hf, hidsum, deg, zflag, batch,
                                                  W1s + (size_t)l * 64 * 512,
                                                  b2u + (size_t)l * H,
                                                  updb + (size_t)l * H,
                                                  lng + (size_t)l * H, lnb + (size_t)l * H,
                                                  W2s + (size_t)nl * 64 * 512,
                                                  hs, hd, hg_sum, hg_maxe,
                                                  (l == NL - 1) ? 1 : 0);
    }

    readout<<<NG, H, 0, stream>>>(hg_sum, hg_maxe, batch,
                                  roW1, rob1, roW2, rob2, roW3, rob3, (float*)d_out);
}

// Round 18
// 449.685 us; speedup vs baseline: 1.0612x; 1.0220x over previous
//
#include <hip/hip_runtime.h>
#include <hip/hip_fp16.h>
#include <math.h>

#define NN 100000
#define NE 500000
#define NG 128
#define ND 91
#define ED 20
#define H  128
#define NL 3
#define EPSF 1e-5f
#define EPB 32          // edges per block in aggregation
#define NB64 ((NN + 63) / 64)
#define NSC ((NN + 1023) / 1024)

typedef _Float16 f16;
typedef _Float16 f16x2 __attribute__((ext_vector_type(2)));
typedef _Float16 f16x8 __attribute__((ext_vector_type(8)));
typedef float    f32x4 __attribute__((ext_vector_type(4)));

// swizzled LDS byte offset for a [64][128] f16 tile (row stride 256 B)
__device__ __forceinline__ int swz(int row, int colbyte) {
    return (row * 256 + colbyte) ^ ((row & 7) << 4);
}

// order-preserving float<->uint for atomicMax
__device__ __forceinline__ unsigned fenc(float f) {
    unsigned u = __float_as_uint(f);
    return (u & 0x80000000u) ? ~u : (u | 0x80000000u);
}
__device__ __forceinline__ float fdec(unsigned key) {
    unsigned u = (key & 0x80000000u) ? (key & 0x7FFFFFFFu) : ~key;
    return __uint_as_float(u);
}

// ---------------------------------------------------------------------------
// Fold edge-feature path: Wec[l] = ee_W @ msg_W1[l][2H:3H,:]
// ---------------------------------------------------------------------------
__global__ void fold_edge_weights(const float* __restrict__ eeW,
                                  const float* __restrict__ eeb,
                                  const float* __restrict__ msgW1,
                                  const float* __restrict__ msgb1,
                                  float* __restrict__ Wec,
                                  float* __restrict__ bec) {
    int l = blockIdx.y;
    int k = blockIdx.x;                        // 0..ED (ED => bias row)
    int c = threadIdx.x;
    const float* W1e = msgW1 + (size_t)l * 3 * H * H + (size_t)2 * H * H;
    if (k < ED) {
        float acc = 0.f;
        for (int m = 0; m < H; ++m) acc += eeW[k * H + m] * W1e[m * H + c];
        Wec[((size_t)l * ED + k) * H + c] = acc;
    } else {
        float acc = msgb1[l * H + c];
        for (int m = 0; m < H; ++m) acc += eeb[m] * W1e[m * H + c];
        bec[(size_t)l * H + c] = acc;
    }
}

// pack Wec into f16 pairs
__global__ void pack_wec(const float* __restrict__ Wec,
                         f16x2* __restrict__ wecp) {
    int l = blockIdx.x, k2 = blockIdx.y, c = threadIdx.x;
    f16x2 v;
    v[0] = (f16)Wec[((size_t)l * ED + 2 * k2) * H + c];
    v[1] = (f16)Wec[((size_t)l * ED + 2 * k2 + 1) * H + c];
    wecp[((size_t)l * (ED / 2) + k2) * H + c] = v;
}

// ---------------------------------------------------------------------------
// Fold msg_W2 into update weights
// ---------------------------------------------------------------------------
__global__ void fold_W2u(const float* __restrict__ msgW2,
                         const float* __restrict__ msgb2,
                         const float* __restrict__ updW,
                         float* __restrict__ W2u,
                         float* __restrict__ b2u) {
    int l = blockIdx.y;
    int k = blockIdx.x;                        // 0..H (H => bias row)
    int c = threadIdx.x;
    const float* Wbot = updW + (size_t)l * 2 * H * H + (size_t)H * H;
    if (k < H) {
        const float* w2row = msgW2 + (size_t)l * H * H + (size_t)k * H;
        float acc = 0.f;
        for (int m = 0; m < H; ++m) acc += w2row[m] * Wbot[m * H + c];
        W2u[((size_t)l * H + k) * H + c] = acc;
    } else {
        const float* b2 = msgb2 + (size_t)l * H;
        float acc = 0.f;
        for (int m = 0; m < H; ++m) acc += b2[m] * Wbot[m * H + c];
        b2u[(size_t)l * H + c] = acc;
    }
}

// ---------------------------------------------------------------------------
// W1s: fragment-major pre-swizzled GEMM1 weights.
// ---------------------------------------------------------------------------
__global__ void make_W1s(const float* __restrict__ updW,
                         const float* __restrict__ W2u,
                         f16* __restrict__ W1s) {
    int l = blockIdx.x, frag = blockIdx.y, lane = threadIdx.x;  // 64 threads
    int cf = frag >> 3, kc = frag & 7;
    int col = cf * 16 + (lane & 15);
    int k0 = kc * 32 + (lane >> 4) * 8;
    f16* out = W1s + ((size_t)l * 64 + frag) * 512 + lane * 8;
    for (int j = 0; j < 8; ++j) {
        int k = k0 + j;
        float v = (k < H) ? updW[(size_t)l * 2 * H * H + (size_t)k * H + col]
                          : W2u[(size_t)l * H * H + (size_t)(k - H) * H + col];
        out[j] = (f16)v;
    }
}

// ---------------------------------------------------------------------------
// W2s: fragment-major pre-swizzled GEMM2 weights.
// ---------------------------------------------------------------------------
__global__ void make_W2s(const float* __restrict__ msgW1,
                         f16* __restrict__ W2s) {
    int l = blockIdx.x, frag = blockIdx.y, lane = threadIdx.x;  // 64 threads
    int wave = frag >> 4, mf = (frag >> 2) & 3, kc = frag & 3;
    int oc = wave * 64 + mf * 16 + (lane & 15);
    int k0 = kc * 32 + (lane >> 4) * 8;
    const float* W1 = msgW1 + (size_t)l * 3 * H * H;
    f16* out = W2s + ((size_t)l * 64 + frag) * 512 + lane * 8;
    for (int j = 0; j < 8; ++j) {
        int k = k0 + j;
        float v = W1[(size_t)((oc < H ? 0 : H) + k) * H + (oc & (H - 1))];
        out[j] = (f16)v;
    }
}

// ---------------------------------------------------------------------------
// Wenc: fragment-major encode weights (K padded 96)
// ---------------------------------------------------------------------------
__global__ void make_Wenc(const float* __restrict__ neW,
                          f16* __restrict__ Wenc) {
    int frag = blockIdx.x, lane = threadIdx.x;  // 24 frags, 64 threads
    int cf = frag / 3, kc = frag % 3;
    int col = cf * 16 + (lane & 15);
    int k0 = kc * 32 + (lane >> 4) * 8;
    f16* out = Wenc + (size_t)frag * 512 + lane * 8;
    for (int j = 0; j < 8; ++j) {
        int k = k0 + j;
        out[j] = (k < ND) ? (f16)neW[(size_t)k * H + col] : (f16)0.f;
    }
}

// ---------------------------------------------------------------------------
// CSR build over dst
// ---------------------------------------------------------------------------
__global__ void csr_count(const int* __restrict__ dst, int* __restrict__ deg) {
    int e = blockIdx.x * blockDim.x + threadIdx.x;
    if (e < NE) atomicAdd(&deg[dst[e]], 1);
}

__global__ void scan_p1(const int* __restrict__ deg,
                        int* __restrict__ part, int* __restrict__ bsum) {
    __shared__ int ws[16];
    int t = threadIdx.x, lane = t & 63, w = t >> 6;
    int i = blockIdx.x * 1024 + t;
    int v = (i < NN) ? deg[i] : 0;
    int inc = v;
    #pragma unroll
    for (int off = 1; off < 64; off <<= 1) {
        int u = __shfl_up(inc, off, 64);
        if (lane >= off) inc += u;
    }
    if (lane == 63) ws[w] = inc;
    __syncthreads();
    if (t == 0) {
        int run = 0;
        #pragma unroll
        for (int q = 0; q < 16; ++q) { int tmp = ws[q]; ws[q] = run; run += tmp; }
        bsum[blockIdx.x] = run;
    }
    __syncthreads();
    if (i < NN) part[i] = ws[w] + inc - v;
}

__global__ void scan_p2(int* __restrict__ bsum) {
    if (threadIdx.x == 0) {
        int run = 0;
        for (int q = 0; q < NSC; ++q) { int tmp = bsum[q]; bsum[q] = run; run += tmp; }
    }
}

__global__ void scan_p3(const int* __restrict__ part, const int* __restrict__ bsum,
                        int* __restrict__ rowstart) {
    int i = blockIdx.x * 1024 + threadIdx.x;
    if (i < NN) rowstart[i] = part[i] + bsum[blockIdx.x];
    if (i == 0) rowstart[NN] = NE;
}

// zflag[n]=1 iff node needs hidsum zero-init (deg0 or receives atomics)
__global__ void mark_zero(const int* __restrict__ rowstart,
                          unsigned char* __restrict__ zflag) {
    int n = blockIdx.x * 256 + threadIdx.x;
    if (n >= NN) return;
    int b = rowstart[n], e = rowstart[n + 1];
    bool interior = (b < e) && (b % EPB != 0) && (e % EPB != 0)
                    && ((b / EPB) == ((e - 1) / EPB));
    zflag[n] = interior ? 0 : 1;
}

// ---------------------------------------------------------------------------
// csr_scatter: one 64B-aligned record per edge slot (single cache line).
// record layout (uint4 x 4, 48B used): {src, dst, ef[0..3]}, {ef[4..11]},
// {ef[12..19]}, pad.
// ---------------------------------------------------------------------------
__global__ void csr_scatter(const int* __restrict__ src,
                            const int* __restrict__ dst,
                            const float* __restrict__ ef,
                            const int* __restrict__ rowstart,
                            int* __restrict__ cursor,
                            uint4* __restrict__ erec) {
    int e = blockIdx.x * blockDim.x + threadIdx.x;
    if (e < NE) {
        int d = dst[e];
        int pos = atomicAdd(&cursor[d], 1);
        int j = rowstart[d] + pos;
        const float* p = ef + (size_t)e * ED;
        union { f16 h[20]; unsigned u[10]; } pk;
        #pragma unroll
        for (int k = 0; k < ED; ++k) pk.h[k] = (f16)p[k];
        uint4* out = erec + (size_t)j * 4;
        out[0] = make_uint4((unsigned)src[e], (unsigned)d, pk.u[0], pk.u[1]);
        out[1] = make_uint4(pk.u[2], pk.u[3], pk.u[4], pk.u[5]);
        out[2] = make_uint4(pk.u[6], pk.u[7], pk.u[8], pk.u[9]);
    }
}

// ---------------------------------------------------------------------------
// GEMM2 device fn: D[outcol 0..255][node 0..63] = W2s(frag-major) x xlds
// ---------------------------------------------------------------------------
__device__ __forceinline__ void gemm2_store(const f16* xlds,
                                            const f16* __restrict__ W2s_l,
                                            f16* __restrict__ hs,
                                            f16* __restrict__ hd,
                                            int n0, int wave, int lane) {
    int g = lane >> 4, r15 = lane & 15;
    f16x8 B2[4][4];
    #pragma unroll
    for (int nf = 0; nf < 4; ++nf) {
        int row = nf * 16 + r15;
        #pragma unroll
        for (int kc = 0; kc < 4; ++kc)
            B2[nf][kc] = *(const f16x8*)((const char*)xlds + swz(row, kc * 64 + g * 16));
    }
    f16* outb = (wave < 2) ? hs : hd;
    int colw = (wave & 1) * 64;
    #pragma unroll
    for (int mf = 0; mf < 4; ++mf) {
        f16x8 A2[4];
        #pragma unroll
        for (int kc = 0; kc < 4; ++kc)
            A2[kc] = *(const f16x8*)&W2s_l[(size_t)(((wave * 4 + mf) * 4 + kc) * 64 + lane) * 8];
        #pragma unroll
        for (int nf = 0; nf < 4; ++nf) {
            f32x4 acc = {0.f, 0.f, 0.f, 0.f};
            #pragma unroll
            for (int kc = 0; kc < 4; ++kc)
                acc = __builtin_amdgcn_mfma_f32_16x16x32_f16(A2[kc], B2[nf][kc], acc, 0, 0, 0);
            int node = n0 + nf * 16 + r15;
            if (node < NN) {
                union { f16 q[4]; uint2 u; } pk;
                pk.q[0] = (f16)acc[0]; pk.q[1] = (f16)acc[1];
                pk.q[2] = (f16)acc[2]; pk.q[3] = (f16)acc[3];
                *(uint2*)&outb[(size_t)node * H + colw + mf * 16 + g * 4] = pk.u;
            }
        }
    }
}

// ---------------------------------------------------------------------------
// Fused encode + msg_pre (64-node tiles); swapped-operand encode GEMM.
// ---------------------------------------------------------------------------
__global__ void __launch_bounds__(256)
encode_pre_mfma(const float* __restrict__ nf,
                const f16* __restrict__ Wenc,
                const float* __restrict__ neb,
                const unsigned char* __restrict__ zflag,
                const f16* __restrict__ W2s_l0,
                f16* __restrict__ hf,
                f16* __restrict__ hs, f16* __restrict__ hd,
                f16* __restrict__ hidsum) {
    __shared__ f16 xlds[64 * 128];
    int t = threadIdx.x;
    int wave = t >> 6, lane = t & 63;
    int g = lane >> 4, r15 = lane & 15;
    int n0 = blockIdx.x * 64;

    // ---- stage nf as f16 pairs: 46 dword writes/row (cols 0..91, 91 pad 0) ----
    for (int i = t; i < 64 * 46; i += 256) {
        int row = i / 46, c2 = i % 46;
        int col = c2 * 2;
        int n = n0 + row;
        float v0 = 0.f, v1 = 0.f;
        if (n < NN) {
            const float* rp = nf + (size_t)n * ND;
            v0 = rp[col];
            v1 = (col + 1 < ND) ? rp[col + 1] : 0.f;
        }
        union { f16 q[2]; unsigned u; } pk;
        pk.q[0] = (f16)v0; pk.q[1] = (f16)v1;
        *(unsigned*)((char*)xlds + swz(row, col * 2)) = pk.u;
    }
    // ---- zero pad cols 92..127 (dword writes) ----
    for (int i = t; i < 64 * 18; i += 256) {
        int row = i / 18, c2 = 46 + i % 18;        // cols 92..126 step 2
        *(unsigned*)((char*)xlds + swz(row, c2 * 4)) = 0u;
    }
    __syncthreads();

    int lrow = wave * 16 + r15;
    f16x8 A[3];
    #pragma unroll
    for (int kc = 0; kc < 3; ++kc)
        A[kc] = *(const f16x8*)((const char*)xlds + swz(lrow, kc * 64 + g * 16));

    f32x4 acc1[8];
    #pragma unroll
    for (int cf = 0; cf < 8; ++cf) acc1[cf] = (f32x4){0.f, 0.f, 0.f, 0.f};
    #pragma unroll
    for (int cf = 0; cf < 8; ++cf) {
        #pragma unroll
        for (int kc = 0; kc < 3; ++kc) {
            f16x8 b = *(const f16x8*)&Wenc[(size_t)((cf * 3 + kc) * 64 + lane) * 8];
            acc1[cf] = __builtin_amdgcn_mfma_f32_16x16x32_f16(b, A[kc], acc1[cf], 0, 0, 0);
        }
    }
    __syncthreads();

    // h = acc + neb -> xlds (packed: node=r15, channels cf*16+g*4..+3)
    #pragma unroll
    for (int cf = 0; cf < 8; ++cf) {
        int m0 = cf * 16 + g * 4;
        float4 nb4 = *(const float4*)&neb[m0];
        union { f16 q[4]; uint2 u; } pk;
        pk.q[0] = (f16)(acc1[cf][0] + nb4.x);
        pk.q[1] = (f16)(acc1[cf][1] + nb4.y);
        pk.q[2] = (f16)(acc1[cf][2] + nb4.z);
        pk.q[3] = (f16)(acc1[cf][3] + nb4.w);
        *(uint2*)((char*)xlds + swz(lrow, m0 * 2)) = pk.u;
    }
    __syncthreads();

    for (int i = t; i < 64 * 32; i += 256) {
        int row = i >> 5, c4 = i & 31;
        int n = n0 + row;
        if (n < NN) {
            uint2 v = *(const uint2*)((const char*)xlds + swz(row, c4 * 8));
            *(uint2*)&hf[(size_t)n * H + c4 * 4] = v;
            if (zflag[n]) *(uint2*)&hidsum[(size_t)n * H + c4 * 4] = make_uint2(0u, 0u);
        }
    }
    gemm2_store(xlds, W2s_l0, hs, hd, n0, wave, lane);
}

// ---------------------------------------------------------------------------
// flush helpers (thread owns channel pair 2t,2t+1)
// ---------------------------------------------------------------------------
__device__ __forceinline__ void flush_store2(f16* __restrict__ hidsum,
                                             int d, int c2, float a, float b) {
    union { f16 q[2]; unsigned u; } pk;
    pk.q[0] = (f16)a; pk.q[1] = (f16)b;
    *(unsigned*)&hidsum[(size_t)d * H + 2 * c2] = pk.u;
}

__device__ __forceinline__ void flush_atomic2(f16* __restrict__ hidsum,
                                              int d, int c2, float a, float b) {
    unsigned* p = (unsigned*)&hidsum[(size_t)d * H + 2 * c2];
    unsigned old = *p;
    while (true) {
        union { f16 q[2]; unsigned u; } cur, nw;
        cur.u = old;
        nw.q[0] = (f16)((float)cur.q[0] + a);
        nw.q[1] = (f16)((float)cur.q[1] + b);
        unsigned prev = atomicCAS(p, old, nw.u);
        if (prev == old) break;
        old = prev;
    }
}

// ---------------------------------------------------------------------------
// Edge-parallel segmented aggregation; 1 wave/block, 2 channels per thread.
// Reads 64B edge records (src, dst, ef f16) staged via single uint4 loop.
// ---------------------------------------------------------------------------
__global__ void __launch_bounds__(64)
aggregate_edges(const uint4* __restrict__ erec,
                const f16* __restrict__ hs,
                const f16* __restrict__ hd,
                const f16x2* __restrict__ wecp_l,
                const float* __restrict__ bec_l,
                f16* __restrict__ hidsum) {
    int t = threadIdx.x;                           // 0..63 -> channels 2t,2t+1
    size_t j0 = (size_t)blockIdx.x * EPB;
    __shared__ uint4 rec[EPB * 4];                 // 2048 B
    {
        const uint4* srcp = erec + j0 * 4;
        for (int i = t; i < EPB * 4; i += 64) rec[i] = srcp[i];
    }
    __syncthreads();
    f16x2 wa[ED / 2], wb[ED / 2];
    #pragma unroll
    for (int k2 = 0; k2 < ED / 2; ++k2) {
        wa[k2] = wecp_l[k2 * H + 2 * t];
        wb[k2] = wecp_l[k2 * H + 2 * t + 1];
    }
    float beca = bec_l[2 * t], becb = bec_l[2 * t + 1];
    f16x2 hv[EPB];
    #pragma unroll
    for (int jj = 0; jj < EPB; ++jj) {
        const int* ri = (const int*)&rec[jj * 4];
        int s = __builtin_amdgcn_readfirstlane(ri[0]);
        int d = __builtin_amdgcn_readfirstlane(ri[1]);
        f16x2 a = *(const f16x2*)&hs[(size_t)s * H + 2 * t];
        f16x2 b = *(const f16x2*)&hd[(size_t)d * H + 2 * t];
        hv[jj] = a + b;                            // v_pk_add_f16
    }
    int dcur = __builtin_amdgcn_readfirstlane(((const int*)&rec[0])[1]);
    float acca = 0.f, accb = 0.f;
    int nflush = 0;
    #pragma unroll
    for (int jj = 0; jj < EPB; ++jj) {
        int d = __builtin_amdgcn_readfirstlane(((const int*)&rec[jj * 4])[1]);
        if (d != dcur) {
            if (nflush == 0) flush_atomic2(hidsum, dcur, t, acca, accb);
            else             flush_store2(hidsum, dcur, t, acca, accb);
            dcur = d; acca = 0.f; accb = 0.f; ++nflush;
        }
        float va = (float)hv[jj][0] + beca;
        float vb = (float)hv[jj][1] + becb;
        const f16x2* ef2 = (const f16x2*)((const char*)&rec[jj * 4] + 8);
        #pragma unroll
        for (int k2 = 0; k2 < ED / 2; ++k2) {
            va = __builtin_amdgcn_fdot2(ef2[k2], wa[k2], va, false);
            vb = __builtin_amdgcn_fdot2(ef2[k2], wb[k2], vb, false);
        }
        acca += fmaxf(va, 0.f);
        accb += fmaxf(vb, 0.f);
    }
    flush_atomic2(hidsum, dcur, t, acca, accb);
}

// ---------------------------------------------------------------------------
// MFMA fused update (64 nodes / 256 threads), swapped-operand GEMM1:
// lane owns node=r15, channels cf*16+g*4..+3 -> packed epilogue.
// last: fused pool (segment sum/max -> hg atomics), no hf write, no GEMM2.
// ---------------------------------------------------------------------------
__global__ void __launch_bounds__(256)
update_pre_mfma(f16* __restrict__ hf,
                f16* __restrict__ hidsum,
                const int* __restrict__ degv,
                const unsigned char* __restrict__ zflag,
                const int* __restrict__ batch,
                const f16* __restrict__ W1s_l,   // frag-major [64][64][8]
                const float* __restrict__ b2u_l,
                const float* __restrict__ updbl,
                const float* __restrict__ lng_l,
                const float* __restrict__ lnb_l,
                const f16* __restrict__ W2s_next,
                f16* __restrict__ hs, f16* __restrict__ hd,
                float* __restrict__ hg_sum, unsigned* __restrict__ hg_maxe,
                int last) {
    __shared__ f16 xlds[64 * 128];
    __shared__ int gbs[64];
    int t = threadIdx.x;
    int wave = t >> 6, lane = t & 63;
    int g = lane >> 4, r15 = lane & 15;
    int n0 = blockIdx.x * 64;

    // ---- A fragments kc4..7 direct from f16 hidsum (coalesced f16x8) ----
    int arow = n0 + wave * 16 + r15;
    bool av = arow < NN;
    f16x8 zero8;
    for (int i = 0; i < 8; ++i) zero8[i] = (f16)0.f;
    f16x8 A1[8];
    #pragma unroll
    for (int kc = 4; kc < 8; ++kc) {
        A1[kc] = av ? *(const f16x8*)&hidsum[(size_t)arow * H + (kc & 3) * 32 + g * 8]
                    : zero8;
    }

    // ---- P1: coalesced stage of hf tile into swizzled LDS ----
    for (int i = t; i < 64 * 32; i += 256) {
        int row = i >> 5, c4 = i & 31;
        int n = n0 + row;
        uint2 v = make_uint2(0u, 0u);
        if (n < NN) v = *(const uint2*)&hf[(size_t)n * H + c4 * 4];
        *(uint2*)((char*)xlds + swz(row, c4 * 8)) = v;
    }
    if (last && t < 64) {
        int n = n0 + t;
        gbs[t] = (n < NN) ? batch[n] : -1;
    }
    __syncthreads();

    // ---- A fragments kc0..3 from xlds ----
    int lrow = wave * 16 + r15;
    #pragma unroll
    for (int kc = 0; kc < 4; ++kc)
        A1[kc] = *(const f16x8*)((const char*)xlds + swz(lrow, kc * 64 + g * 16));

    // ---- GEMM1 swapped: acc1[cf][r] = channel cf*16+g*4+r of node r15 ----
    f32x4 acc1[8];
    #pragma unroll
    for (int cf = 0; cf < 8; ++cf) acc1[cf] = (f32x4){0.f, 0.f, 0.f, 0.f};
    #pragma unroll
    for (int cf = 0; cf < 8; ++cf) {
        #pragma unroll
        for (int kc = 0; kc < 8; ++kc) {
            f16x8 b = *(const f16x8*)&W1s_l[(size_t)((cf * 8 + kc) * 64 + lane) * 8];
            acc1[cf] = __builtin_amdgcn_mfma_f32_16x16x32_f16(b, A1[kc], acc1[cf], 0, 0, 0);
        }
    }

    // ---- packed epilogue: one node per lane ----
    int node = n0 + lrow;
    bool nv = node < NN;
    float degf = nv ? (float)degv[node] : 0.f;
    float x[8][4];
    float s1 = 0.f, s2 = 0.f;
    #pragma unroll
    for (int cf = 0; cf < 8; ++cf) {
        int m0 = cf * 16 + g * 4;
        float4 ub4 = *(const float4*)&updbl[m0];
        float4 b24 = *(const float4*)&b2u_l[m0];
        union { f16 q[4]; uint2 u; } hres;
        hres.u = *(const uint2*)((const char*)xlds + swz(lrow, m0 * 2));
        const float* ubp = (const float*)&ub4;
        const float* b2p = (const float*)&b24;
        #pragma unroll
        for (int r = 0; r < 4; ++r) {
            float xr = (float)hres.q[r]
                     + fmaxf(acc1[cf][r] + ubp[r] + degf * b2p[r], 0.f);
            x[cf][r] = xr;
            s1 += xr; s2 += xr * xr;
        }
    }
    s1 += __shfl_xor(s1, 16); s2 += __shfl_xor(s2, 16);
    s1 += __shfl_xor(s1, 32); s2 += __shfl_xor(s2, 32);
    float mu  = s1 * (1.0f / H);
    float var = s2 * (1.0f / H) - mu * mu;
    float inv = rsqrtf(var + EPSF);
    #pragma unroll
    for (int cf = 0; cf < 8; ++cf) {
        int m0 = cf * 16 + g * 4;
        float4 g4  = *(const float4*)&lng_l[m0];
        float4 bl4 = *(const float4*)&lnb_l[m0];
        const float* gp = (const float*)&g4;
        const float* bp = (const float*)&bl4;
        union { f16 q[4]; uint2 u; } pk;
        #pragma unroll
        for (int r = 0; r < 4; ++r)
            pk.q[r] = (f16)((x[cf][r] - mu) * inv * gp[r] + bp[r]);
        *(uint2*)((char*)xlds + swz(lrow, m0 * 2)) = pk.u;
    }
    __syncthreads();

    if (last) {
        // ---- fused pool: segment sum/max over sorted batch ids ----
        int c = t & 127, q = t >> 7;               // q: rows 0..31 / 32..63
        float s = 0.f, mx = -INFINITY;
        int gcur = -1;
        for (int r = 0; r < 32; ++r) {
            int row = q * 32 + r;
            if (n0 + row >= NN) break;
            int gb = gbs[row];
            if (gb != gcur) {
                if (gcur >= 0) {
                    atomicAdd(&hg_sum[(size_t)gcur * H + c], s);
                    atomicMax(&hg_maxe[(size_t)gcur * H + c], fenc(mx));
                }
                gcur = gb; s = 0.f; mx = -INFINITY;
            }
            float v = (float)*(const f16*)((const char*)xlds + swz(row, c * 2));
            s += v; mx = fmaxf(mx, v);
        }
        if (gcur >= 0) {
            atomicAdd(&hg_sum[(size_t)gcur * H + c], s);
            atomicMax(&hg_maxe[(size_t)gcur * H + c], fenc(mx));
        }
        return;
    }

    // ---- coalesced hf write-back (+ flagged hidsum zero) ----
    for (int i = t; i < 64 * 32; i += 256) {
        int row = i >> 5, c4 = i & 31;
        int n = n0 + row;
        if (n < NN) {
            uint2 v = *(const uint2*)((const char*)xlds + swz(row, c4 * 8));
            *(uint2*)&hf[(size_t)n * H + c4 * 4] = v;
            if (zflag[n]) *(uint2*)&hidsum[(size_t)n * H + c4 * 4] = make_uint2(0u, 0u);
        }
    }
    gemm2_store(xlds, W2s_next, hs, hd, n0, wave, lane);
}

// ---------------------------------------------------------------------------
// readout MLP; computes mean from hg_sum/(cnt+1), decodes max
// ---------------------------------------------------------------------------
__global__ void __launch_bounds__(128)
readout(const float* __restrict__ hg_sum,
        const unsigned* __restrict__ hg_maxe,
        const int* __restrict__ batch,
        const float* __restrict__ W1, const float* __restrict__ b1,
        const float* __restrict__ W2, const float* __restrict__ b2,
        const float* __restrict__ W3, const float* __restrict__ b3,
        float* __restrict__ out) {
    int g = blockIdx.x, t = threadIdx.x;
    __shared__ float xin[2 * H];
    __shared__ float x1[H];
    __shared__ float x2[H / 2];
    int lo = 0, hi = NN;
    while (lo < hi) { int mid = (lo + hi) >> 1; if (batch[mid] < g) lo = mid + 1; else hi = mid; }
    int start = lo;
    hi = NN;
    while (lo < hi) { int mid = (lo + hi) >> 1; if (batch[mid] < g + 1) lo = mid + 1; else hi = mid; }
    float denom = (float)(lo - start) + 1.0f;
    xin[t]     = hg_sum[(size_t)g * H + t] / denom;
    xin[H + t] = fdec(hg_maxe[(size_t)g * H + t]);
    __syncthreads();
    float acc = b1[t];
    for (int k = 0; k < 2 * H; ++k) acc += xin[k] * W1[k * H + t];
    x1[t] = fmaxf(acc, 0.f);
    __syncthreads();
    if (t < 64) {
        float a2 = b2[t];
        for (int k = 0; k < H; ++k) a2 += x1[k] * W2[k * 64 + t];
        x2[t] = fmaxf(a2, 0.f);
    }
    __syncthreads();
    if (t < 64) {
        float v = x2[t] * W3[t];
        #pragma unroll
        for (int off = 32; off >= 1; off >>= 1) v += __shfl_xor(v, off, 64);
        if (t == 0) out[g] = v + b3[0];
    }
}

// ---------------------------------------------------------------------------
extern "C" void kernel_launch(void* const* d_in, const int* in_sizes, int n_in,
                              void* d_out, int out_size, void* d_ws, size_t ws_size,
                              hipStream_t stream) {
    const float* node_feats = (const float*)d_in[0];
    const int*   edge_index = (const int*)d_in[1];
    const float* edge_feats = (const float*)d_in[2];
    const int*   batch      = (const int*)d_in[3];
    const float* ne_W  = (const float*)d_in[4];
    const float* ne_b  = (const float*)d_in[5];
    const float* ee_W  = (const float*)d_in[6];
    const float* ee_b  = (const float*)d_in[7];
    const float* msgW1 = (const float*)d_in[8];
    const float* msgb1 = (const float*)d_in[9];
    const float* msgW2 = (const float*)d_in[10];
    const float* msgb2 = (const float*)d_in[11];
    const float* updW  = (const float*)d_in[12];
    const float* updb  = (const float*)d_in[13];
    const float* lng   = (const float*)d_in[14];
    const float* lnb   = (const float*)d_in[15];
    const float* roW1  = (const float*)d_in[16];
    const float* rob1  = (const float*)d_in[17];
    const float* roW2  = (const float*)d_in[18];
    const float* rob2  = (const float*)d_in[19];
    const float* roW3  = (const float*)d_in[20];
    const float* rob3  = (const float*)d_in[21];

    const int* src = edge_index;            // row 0
    const int* dst = edge_index + NE;       // row 1

    char* ws = (char*)d_ws;
    f16*   hf     = (f16*)ws;   ws += (size_t)NN * H * 2;
    f16*   hidsum = (f16*)ws;   ws += (size_t)NN * H * 2;
    f16*   hs     = (f16*)ws;   ws += (size_t)NN * H * 2;
    f16*   hd     = (f16*)ws;   ws += (size_t)NN * H * 2;
    uint4* erec   = (uint4*)ws; ws += (size_t)NE * 64;
    int* rowstart = (int*)ws; ws += (size_t)(NN + 4) * 4;
    int* deg      = (int*)ws; ws += (size_t)NN * 4;     // reused as cursor; ends = degree
    int* part     = (int*)ws; ws += (size_t)NN * 4;
    int* bsum     = (int*)ws; ws += (size_t)256 * 4;
    unsigned char* zflag = (unsigned char*)ws; ws += ((size_t)NN + 15) / 16 * 16;
    float* Wec = (float*)ws; ws += (size_t)NL * ED * H * 4;
    float* bec = (float*)ws; ws += (size_t)NL * H * 4;
    f16x2* wecp = (f16x2*)ws; ws += (size_t)NL * (ED / 2) * H * 4;
    float* W2u = (float*)ws; ws += (size_t)NL * H * H * 4;
    float* b2u = (float*)ws; ws += (size_t)NL * H * 4;
    f16* W1s = (f16*)ws; ws += (size_t)NL * 64 * 512 * 2;
    f16* W2s = (f16*)ws; ws += (size_t)NL * 64 * 512 * 2;
    f16* Wenc = (f16*)ws; ws += (size_t)24 * 512 * 2;
    float*    hg_sum  = (float*)ws;    ws += (size_t)NG * H * 4;
    unsigned* hg_maxe = (unsigned*)ws; ws += (size_t)NG * H * 4;

    // --- precompute: folded weights + packed/frag-major f16 weights + CSR ---
    fold_edge_weights<<<dim3(ED + 1, NL), H, 0, stream>>>(ee_W, ee_b, msgW1, msgb1, Wec, bec);
    pack_wec<<<dim3(NL, ED / 2), H, 0, stream>>>(Wec, wecp);
    fold_W2u<<<dim3(H + 1, NL), H, 0, stream>>>(msgW2, msgb2, updW, W2u, b2u);
    make_W1s<<<dim3(NL, 64), 64, 0, stream>>>(updW, W2u, W1s);
    make_W2s<<<dim3(NL, 64), 64, 0, stream>>>(msgW1, W2s);
    make_Wenc<<<24, 64, 0, stream>>>(ne_W, Wenc);

    hipMemsetAsync(deg, 0, (size_t)NN * 4, stream);
    hipMemsetAsync(hg_sum, 0, (size_t)NG * H * 8, stream);   // sum + maxe (adjacent)
    csr_count<<<(NE + 255) / 256, 256, 0, stream>>>(dst, deg);
    scan_p1<<<NSC, 1024, 0, stream>>>(deg, part, bsum);
    scan_p2<<<1, 64, 0, stream>>>(bsum);
    scan_p3<<<NSC, 1024, 0, stream>>>(part, bsum, rowstart);
    mark_zero<<<(NN + 255) / 256, 256, 0, stream>>>(rowstart, zflag);
    hipMemsetAsync(deg, 0, (size_t)NN * 4, stream);
    csr_scatter<<<(NE + 255) / 256, 256, 0, stream>>>(src, dst, edge_feats, rowstart,
                                                      deg, erec);

    encode_pre_mfma<<<NB64, 256, 0, stream>>>(node_feats, Wenc, ne_b, zflag,
                                              W2s, hf, hs, hd, hidsum);

    // --- layers ---
    for (int l = 0; l < NL; ++l) {
        aggregate_edges<<<NE / EPB, 64, 0, stream>>>(erec, hs, hd,
                                                     wecp + (size_t)l * (ED / 2) * H,
                                                     bec + (size_t)l * H, hidsum);
        int nl = (l + 1 < NL) ? (l + 1) : 0;   // safe index; unused when last
        update_pre_mfma<<<NB64, 256, 0, stream>>>(hf, hidsum, deg, zflag, batch,
                                                  W1s + (size_t)l * 64 * 512,
                                                  b2u + (size_t)l * H,
                                                  updb + (size_t)l * H,
                                                  lng + (size_t)l * H, lnb + (size_t)l * H,
                                                  W2s + (size_t)nl * 64 * 512,
                                                  hs, hd, hg_sum, hg_maxe,
                                                  (l == NL - 1) ? 1 : 0);
    }

    readout<<<NG, H, 0, stream>>>(hg_sum, hg_maxe, batch,
                                  roW1, rob1, roW2, rob2, roW3, rob3, (float*)d_out);
}